// Round 12
// baseline (814.807 us; speedup 1.0000x reference)
//
#include <hip/hip_runtime.h>

#define NB 4
#define NN 50000

// ---- workspace byte offsets (total ~180.8 MB, < proven 205.9 MB) ----
#define H0B    0L
#define H1B    51200000L
#define QB     102400000L
#define KKB    128000000L    // k' (unfinalized, bf16)
#define RMB    153600000L    // fp32 rm [4*50000]
#define WBFB   154400000L    // bf16 GLU weights: layer0 [256][128], layer1 at +65536B
#define GMB    154794240L    // 4 uints
#define W12B   154795264L    // bf16: W1 [32][96], W2 [32][96], proj [64][32], W_regT [16][256]
#define V2TB   154819840L    // bf16 v2x^T+ksum [4][144][64]
#define PARTB  154893568L    // fp32 v2x partials [4][196][8192]
#define KPARTB 180583680L    // fp32 ksum partials [4][196][64]

typedef short short8_t __attribute__((ext_vector_type(8)));
typedef float f32x4 __attribute__((ext_vector_type(4)));

__device__ __forceinline__ unsigned short f2bf(float f){
  unsigned u = __float_as_uint(f);
  return (unsigned short)((u + 0x7FFFu + ((u>>16)&1u)) >> 16);
}
__device__ __forceinline__ float bf2f(unsigned short s){
  return __uint_as_float(((unsigned)s)<<16);
}
__device__ __forceinline__ unsigned pk2(float a, float b){
  return (unsigned)f2bf(a) | ((unsigned)f2bf(b)<<16);
}
__device__ __forceinline__ uint4 pk8(const float* f){
  uint4 o; o.x=pk2(f[0],f[1]); o.y=pk2(f[2],f[3]);
  o.z=pk2(f[4],f[5]); o.w=pk2(f[6],f[7]); return o;
}
__device__ __forceinline__ void up8(uint4 v, float* f){
  f[0]=bf2f((unsigned short)(v.x&0xFFFFu)); f[1]=bf2f((unsigned short)(v.x>>16));
  f[2]=bf2f((unsigned short)(v.y&0xFFFFu)); f[3]=bf2f((unsigned short)(v.y>>16));
  f[4]=bf2f((unsigned short)(v.z&0xFFFFu)); f[5]=bf2f((unsigned short)(v.z>>16));
  f[6]=bf2f((unsigned short)(v.w&0xFFFFu)); f[7]=bf2f((unsigned short)(v.w>>16));
}
__device__ __forceinline__ short8_t relu8(short8_t s){
  short8_t r;
  #pragma unroll
  for (int i=0;i<8;i++){ short v = s[i]; r[i] = (v & (short)0x8000) ? (short)0 : v; }
  return r;
}
__device__ __forceinline__ short8_t ld8u32(const unsigned short* p){
  union { unsigned u[4]; short8_t s; } t;
  #pragma unroll
  for (int q=0;q<4;q++) t.u[q] = *(const unsigned*)(p + q*2);
  return t.s;
}
__device__ __forceinline__ unsigned encOrd(float f){
  unsigned u = __float_as_uint(f);
  return (u & 0x80000000u) ? ~u : (u | 0x80000000u);
}
__device__ __forceinline__ float decOrd(unsigned u){
  return (u & 0x80000000u) ? __uint_as_float(u & 0x7fffffffu)
                           : __uint_as_float(~u);
}

// ---- zero gmax ----
__global__ void k_init(char* __restrict__ wsb){
  if (threadIdx.x < 4) ((unsigned*)(wsb + GMB))[threadIdx.x] = 0u;
}
// ---- GLU weights -> bf16 [n][k] ----
__global__ void k_wcvt(const float* __restrict__ wi0, const float* __restrict__ wo0,
                       const float* __restrict__ wi1, const float* __restrict__ wo1,
                       char* __restrict__ wsb){
  int idx = blockIdx.x*256 + threadIdx.x;
  if (idx >= 65536) return;
  int l = idx >> 15, r = (idx >> 7) & 255, c = idx & 127;
  const float* src = (l==0) ? ((r<128)? wi0 : wo0) : ((r<128)? wi1 : wo1);
  float v = src[(r&127)*128 + c];
  ((unsigned short*)(wsb + WBFB))[l*32768 + r*128 + c] = f2bf(v);
}
// ---- W1,W2 [32][96], proj [64][32], W_regT [16][256] -> bf16 --------------
__global__ void k_wcvt2(const float* __restrict__ W1, const float* __restrict__ W2,
                        const float* __restrict__ proj, const float* __restrict__ W_reg,
                        char* __restrict__ wsb){
  int i = blockIdx.x*256 + threadIdx.x;          // 12288 total
  if (i >= 12288) return;
  unsigned short* dst = (unsigned short*)(wsb + W12B);
  float v;
  if (i < 3072) v = W1[i];
  else if (i < 6144) v = W2[i-3072];
  else if (i < 8192) v = proj[i-6144];
  else {
    int r = (i-8192) >> 8, c = (i-8192) & 255;
    v = (r < 12) ? W_reg[r*256 + c] : 0.f;
  }
  dst[i] = f2bf(v);
}

// ---------- pass1a: h0 (W_in matmul + embeddings) --------------------------
__global__ __launch_bounds__(256) void k_pass1a(
  const float* __restrict__ x, const float* __restrict__ node_emb,
  const float* __restrict__ time_emb, const float* __restrict__ week_emb,
  const float* __restrict__ W_in, const float* __restrict__ b_in,
  char* __restrict__ wsb)
{
  const int b = blockIdx.y;
  const int n = blockIdx.x*256 + threadIdx.x;
  if (n >= NN) return;
  const long row = (long)b*NN + n;
  float xr[36];
  {
    const float4* xp = (const float4*)(x + row*36);
    #pragma unroll
    for (int i=0;i<9;i++){ float4 t=xp[i]; xr[4*i]=t.x; xr[4*i+1]=t.y; xr[4*i+2]=t.z; xr[4*i+3]=t.w; }
  }
  int tidx = (int)(xr[34]*288.0f); tidx = tidx<0?0:(tidx>287?287:tidx);
  int widx = (int)(xr[35]);        widx = widx<0?0:(widx>6?6:widx);
  uint4* h0q = (uint4*)(wsb + H0B) + row*16;
  float hh[32];
  #pragma unroll 1
  for (int jj=0;jj<8;jj++){
    #pragma unroll
    for (int jl=0;jl<4;jl++){
      const int j = jj*4+jl;
      const float* w = W_in + j*36;
      float a0=0.f,a1=0.f,a2=0.f,a3=0.f;
      #pragma unroll
      for (int i=0;i<36;i+=4){ a0+=xr[i]*w[i]; a1+=xr[i+1]*w[i+1]; a2+=xr[i+2]*w[i+2]; a3+=xr[i+3]*w[i+3]; }
      hh[j] = b_in[j] + ((a0+a1)+(a2+a3));
    }
  }
  #pragma unroll
  for (int c=0;c<4;c++) h0q[c] = pk8(hh + 8*c);
  float xg[96];
  {
    const float4* p0 = (const float4*)(node_emb + (long)n*32);
    const float4* p1 = (const float4*)(time_emb + (long)tidx*32);
    const float4* p2 = (const float4*)(week_emb + (long)widx*32);
    #pragma unroll
    for (int i=0;i<8;i++){ float4 t=p0[i]; xg[4*i]=t.x; xg[4*i+1]=t.y; xg[4*i+2]=t.z; xg[4*i+3]=t.w; }
    #pragma unroll
    for (int i=0;i<8;i++){ float4 t=p1[i]; xg[32+4*i]=t.x; xg[32+4*i+1]=t.y; xg[32+4*i+2]=t.z; xg[32+4*i+3]=t.w; }
    #pragma unroll
    for (int i=0;i<8;i++){ float4 t=p2[i]; xg[64+4*i]=t.x; xg[64+4*i+1]=t.y; xg[64+4*i+2]=t.z; xg[64+4*i+3]=t.w; }
  }
  #pragma unroll
  for (int c=0;c<12;c++) h0q[4+c] = pk8(xg + 8*c);
}

// ---------- pass1b (MFMA): q, k', rm, global key max -----------------------
__global__ __launch_bounds__(256) void k_pass1b(
  const float* __restrict__ b1, const float* __restrict__ b2,
  char* __restrict__ wsb)
{
  __shared__ unsigned short xgt[64][104];
  __shared__ unsigned short dt[2][64][40];
  __shared__ unsigned short ot[64][72];
  __shared__ float wred[4];
  const int b   = blockIdx.y;
  const int tid = threadIdx.x;
  const int lane= tid & 63;
  const int w   = tid >> 6;
  const int c   = lane & 15;
  const int kg  = lane >> 4;
  const long r0blk = (long)blockIdx.x * 64;
  {
    int row = tid >> 2, q3 = tid & 3;
    long gr = r0blk + row;
    uint4 v0={0,0,0,0}, v1=v0, v2=v0;
    if (gr < NN){
      const uint4* src = (const uint4*)(wsb + H0B + ((long)b*NN + gr)*256 + 64 + q3*48);
      v0=src[0]; v1=src[1]; v2=src[2];
    }
    uint4* d = (uint4*)&xgt[row][q3*24];
    d[0]=v0; d[1]=v1; d[2]=v2;
  }
  __syncthreads();
  const unsigned short* w1bf = (const unsigned short*)(wsb + W12B);
  const unsigned short* w2bf = w1bf + 3072;
  const unsigned short* pjbf = w1bf + 6144;
  f32x4 accd[2][2];
  #pragma unroll
  for (int s=0;s<2;s++)
    #pragma unroll
    for (int f=0;f<2;f++) accd[s][f] = (f32x4){0.f,0.f,0.f,0.f};
  #pragma unroll
  for (int ks=0;ks<3;ks++){
    short8_t a = *(const short8_t*)&xgt[w*16 + c][ks*32 + kg*8];
    #pragma unroll
    for (int f=0;f<2;f++){
      short8_t bw1 = *(const short8_t*)(w1bf + (f*16+c)*96 + ks*32 + kg*8);
      accd[0][f] = __builtin_amdgcn_mfma_f32_16x16x32_bf16(a, bw1, accd[0][f], 0,0,0);
      short8_t bw2 = *(const short8_t*)(w2bf + (f*16+c)*96 + ks*32 + kg*8);
      accd[1][f] = __builtin_amdgcn_mfma_f32_16x16x32_bf16(a, bw2, accd[1][f], 0,0,0);
    }
  }
  const float DSC = 0.42044820762685725f;   // 32^-0.25
  float dv[2][2][4];
  #pragma unroll
  for (int f=0;f<2;f++){
    float bb1 = b1[f*16+c], bb2 = b2[f*16+c];
    #pragma unroll
    for (int jj=0;jj<4;jj++){
      dv[0][f][jj] = (accd[0][f][jj] + bb1) * DSC;
      dv[1][f][jj] = (accd[1][f][jj] + bb2) * DSC;
    }
  }
  float dg[2][4];
  #pragma unroll
  for (int s=0;s<2;s++)
    #pragma unroll
    for (int jj=0;jj<4;jj++){
      float t = dv[s][0][jj]*dv[s][0][jj] + dv[s][1][jj]*dv[s][1][jj];
      #pragma unroll
      for (int off=1; off<16; off<<=1) t += __shfl_xor(t, off);
      dg[s][jj] = 0.5f * t;
    }
  #pragma unroll
  for (int s=0;s<2;s++)
    #pragma unroll
    for (int f=0;f<2;f++)
      #pragma unroll
      for (int jj=0;jj<4;jj++)
        dt[s][w*16 + kg*4 + jj][f*16 + c] = f2bf(dv[s][f][jj]);
  __syncthreads();
  f32x4 acc2[2][4];
  #pragma unroll
  for (int s=0;s<2;s++){
    short8_t ad = *(const short8_t*)&dt[s][w*16 + c][kg*8];
    #pragma unroll
    for (int f=0;f<4;f++){
      short8_t bp = *(const short8_t*)(pjbf + (f*16+c)*32 + kg*8);
      acc2[s][f] = __builtin_amdgcn_mfma_f32_16x16x32_bf16(ad, bp, (f32x4){0.f,0.f,0.f,0.f}, 0,0,0);
    }
  }
  float mx[2][4];
  #pragma unroll
  for (int s=0;s<2;s++)
    #pragma unroll
    for (int jj=0;jj<4;jj++){
      float t = fmaxf(fmaxf(acc2[s][0][jj],acc2[s][1][jj]),
                      fmaxf(acc2[s][2][jj],acc2[s][3][jj]));
      #pragma unroll
      for (int off=1; off<16; off<<=1) t = fmaxf(t, __shfl_xor(t, off));
      mx[s][jj] = t;
    }
  #pragma unroll
  for (int f=0;f<4;f++)
    #pragma unroll
    for (int jj=0;jj<4;jj++){
      float qv = 0.125f*(__expf(acc2[0][f][jj] - dg[0][jj] - mx[0][jj]) + 1e-6f);
      ot[w*16 + kg*4 + jj][f*16 + c] = f2bf(qv);
    }
  __syncthreads();
  {
    int row = tid >> 2, q3 = tid & 3;
    long gr = r0blk + row;
    if (gr < NN){
      const uint4* s = (const uint4*)&ot[row][q3*16];
      uint4* dst = (uint4*)((unsigned short*)(wsb + QB) + ((long)b*NN + gr)*64 + q3*16);
      dst[0] = s[0]; dst[1] = s[1];
    }
  }
  __syncthreads();
  float bmax = -3.0e38f;
  #pragma unroll
  for (int f=0;f<4;f++)
    #pragma unroll
    for (int jj=0;jj<4;jj++){
      float kv = __expf(acc2[1][f][jj] - mx[1][jj]);
      ot[w*16 + kg*4 + jj][f*16 + c] = f2bf(kv);
    }
  #pragma unroll
  for (int jj=0;jj<4;jj++){
    long gr = r0blk + w*16 + kg*4 + jj;
    bool val = (gr < NN);
    if (val && c==0)
      ((float*)(wsb + RMB))[(long)b*NN + gr] = mx[1][jj] - dg[1][jj];
    if (val) bmax = fmaxf(bmax, mx[1][jj]);
  }
  #pragma unroll
  for (int off=32; off>0; off>>=1) bmax = fmaxf(bmax, __shfl_xor(bmax, off));
  if (lane==0) wred[w] = bmax;
  __syncthreads();
  {
    int row = tid >> 2, q3 = tid & 3;
    long gr = r0blk + row;
    if (gr < NN){
      const uint4* s = (const uint4*)&ot[row][q3*16];
      uint4* dst = (uint4*)((unsigned short*)(wsb + KKB) + ((long)b*NN + gr)*64 + q3*16);
      dst[0] = s[0]; dst[1] = s[1];
    }
  }
  if (tid==0){
    float m2 = fmaxf(fmaxf(wred[0],wred[1]), fmaxf(wred[2],wred[3]));
    atomicMax((unsigned*)(wsb + GMB) + b, encOrd(m2));
  }
}

// ---------- fused GLU + k-finalize + MFMA reduce (named regs, no spill) ----
template<int KSUM>
__global__ __launch_bounds__(256, 4) void k_glured(
  char* __restrict__ wsb, const unsigned short* __restrict__ hsrc,
  const unsigned short* __restrict__ wbf,
  const float* __restrict__ bi, const float* __restrict__ bo,
  float* __restrict__ part, float* __restrict__ kpart)
{
  __shared__ unsigned short ht[64][132];     // 16896 B; ktl[64][70] aliases it
  __shared__ unsigned short htT[144][72];    // rows 128..143: ones row + zeros (KSUM)
  unsigned short (*ktl)[70] = (unsigned short(*)[70])&ht[0][0];
  const int b = blockIdx.y;
  const int tid = threadIdx.x;
  const int lane = tid & 63;
  const int w = tid >> 6;
  const int c = lane & 15;
  const int kg = lane >> 4;
  const float gm = decOrd(((const unsigned*)(wsb + GMB))[b]);
  const float* rm = (const float*)(wsb + RMB) + (long)b*NN;
  const uint4* kbase = (const uint4*)(wsb + KKB) + (long)b*NN*8;
  if (KSUM){
    for (int i = tid; i < 16*72; i += 256){
      int r = i/72, col = i%72;
      htT[128+r][col] = (r==0) ? (unsigned short)0x3F80 : (unsigned short)0;
    }
  }
  const f32x4 z4 = (f32x4){0.f,0.f,0.f,0.f};
  f32x4 r0_=z4, r1_=z4, r2_=z4, r3_=z4, r4_=z4, r5_=z4, r6_=z4, r7_=z4, r8_=z4;
  float bi_l[8], bo_l[8];
  #pragma unroll
  for (int f=0;f<8;f++){ bi_l[f] = bi[f*16+c]; bo_l[f] = bo[f*16+c]; }
  const int krr = tid>>3, kcc = tid&7;       // this thread's k-staging coords
  #pragma unroll 1
  for (int t=0;t<4;t++){
    const long r0 = (long)blockIdx.x*256 + t*64;
    // hoist finalized k into named regs (rows krr, krr+32)
    uint4 kpA, kpB;
    {
      float tv[8];
      long grA = r0 + krr;
      if (grA < NN){
        uint4 raw = kbase[grA*8 + kcc];
        float scale = __expf(rm[grA] - gm);
        up8(raw, tv);
        #pragma unroll
        for (int i=0;i<8;i++) tv[i] = 0.125f*(tv[i]*scale + 1e-6f);
      } else {
        #pragma unroll
        for (int i=0;i<8;i++) tv[i] = 0.f;
      }
      kpA = pk8(tv);
      long grB = r0 + krr + 32;
      if (grB < NN){
        uint4 raw = kbase[grB*8 + kcc];
        float scale = __expf(rm[grB] - gm);
        up8(raw, tv);
        #pragma unroll
        for (int i=0;i<8;i++) tv[i] = 0.125f*(tv[i]*scale + 1e-6f);
      } else {
        #pragma unroll
        for (int i=0;i<8;i++) tv[i] = 0.f;
      }
      kpB = pk8(tv);
    }
    { // stage h tile
      int row = tid>>2, q3 = tid&3;
      long gr = r0 + row;
      uint4 v0={0,0,0,0},v1=v0,v2=v0,v3=v0;
      if (gr < NN){
        const uint4* src = (const uint4*)(hsrc + ((long)b*NN + gr)*128 + q3*32);
        v0=src[0]; v1=src[1]; v2=src[2]; v3=src[3];
      }
      uint4* d = (uint4*)&ht[row][q3*32];
      d[0]=v0; d[1]=v1; d[2]=v2; d[3]=v3;
    }
    __syncthreads();
    // GLU in quarters (2 gi + 2 go accumulators live at a time)
    #pragma unroll
    for (int q=0; q<4; q++){
      f32x4 giA=z4, giB=z4, goA=z4, goB=z4;
      #pragma unroll
      for (int ks=0;ks<4;ks++){
        short8_t a = *(const short8_t*)&ht[w*16 + c][ks*32 + kg*8];
        short8_t bwiA = *(const short8_t*)(wbf + ((q*2  )*16 + c)*128 + ks*32 + kg*8);
        giA = __builtin_amdgcn_mfma_f32_16x16x32_bf16(a, bwiA, giA, 0, 0, 0);
        short8_t bwiB = *(const short8_t*)(wbf + ((q*2+1)*16 + c)*128 + ks*32 + kg*8);
        giB = __builtin_amdgcn_mfma_f32_16x16x32_bf16(a, bwiB, giB, 0, 0, 0);
        short8_t bwoA = *(const short8_t*)(wbf + ((q*2+8)*16 + c)*128 + ks*32 + kg*8);
        goA = __builtin_amdgcn_mfma_f32_16x16x32_bf16(a, bwoA, goA, 0, 0, 0);
        short8_t bwoB = *(const short8_t*)(wbf + ((q*2+9)*16 + c)*128 + ks*32 + kg*8);
        goB = __builtin_amdgcn_mfma_f32_16x16x32_bf16(a, bwoB, goB, 0, 0, 0);
      }
      #pragma unroll
      for (int j=0;j<4;j++){
        bool val = (r0 + w*16 + kg*4 + j) < NN;
        float aa = giA[j] + bi_l[q*2];
        float cc2= goA[j] + bo_l[q*2];
        float oA = cc2 / (1.0f + __expf(-aa));
        htT[(q*2  )*16 + c][w*16 + kg*4 + j] = val ? f2bf(oA) : (unsigned short)0;
        float ab = giB[j] + bi_l[q*2+1];
        float cb = goB[j] + bo_l[q*2+1];
        float oB = cb / (1.0f + __expf(-ab));
        htT[(q*2+1)*16 + c][w*16 + kg*4 + j] = val ? f2bf(oB) : (unsigned short)0;
      }
    }
    __syncthreads();   // all ht reads done -> safe to overwrite with ktl
    {
      const unsigned kvA[4] = {kpA.x, kpA.y, kpA.z, kpA.w};
      const unsigned kvB[4] = {kpB.x, kpB.y, kpB.z, kpB.w};
      #pragma unroll
      for (int i=0;i<8;i++){
        unsigned short uA = (i&1) ? (unsigned short)(kvA[i>>1]>>16)
                                  : (unsigned short)(kvA[i>>1]&0xFFFFu);
        ktl[kcc*8+i][krr] = uA;
        unsigned short uB = (i&1) ? (unsigned short)(kvB[i>>1]>>16)
                                  : (unsigned short)(kvB[i>>1]&0xFFFFu);
        ktl[kcc*8+i][krr + 32] = uB;
      }
    }
    __syncthreads();   // ktl ready
    // reduce MFMA with named accumulators (KSUM: r8_ = ones row -> ksum)
    #pragma unroll
    for (int ks=0;ks<2;ks++){
      short8_t a = ld8u32(&ktl[w*16 + c][ks*32 + kg*8]);
      #define RED1(FI, RV) { short8_t bb = *(const short8_t*)&htT[(FI)*16 + c][ks*32 + kg*8]; \
                             RV = __builtin_amdgcn_mfma_f32_16x16x32_bf16(a, bb, RV, 0, 0, 0); }
      RED1(0, r0_) RED1(1, r1_) RED1(2, r2_) RED1(3, r3_)
      RED1(4, r4_) RED1(5, r5_) RED1(6, r6_) RED1(7, r7_)
      if (KSUM) RED1(8, r8_)
      #undef RED1
    }
    __syncthreads();   // loop WAR (next tile overwrites ht/ktl, htT)
  }
  // plain coalesced partial store (no atomics)
  float* pdst = part + ((long)b*196 + blockIdx.x)*8192;
  #define STORE1(FI, RV) { \
    _Pragma("unroll") \
    for (int j=0;j<4;j++) pdst[(w*16 + kg*4 + j)*128 + (FI)*16 + c] = RV[j]; }
  STORE1(0, r0_) STORE1(1, r1_) STORE1(2, r2_) STORE1(3, r3_)
  STORE1(4, r4_) STORE1(5, r5_) STORE1(6, r6_) STORE1(7, r7_)
  #undef STORE1
  if (KSUM && c == 0){
    float* kdst = kpart + ((long)b*196 + blockIdx.x)*64;
    #pragma unroll
    for (int j=0;j<4;j++)
      kdst[w*16 + kg*4 + j] = r8_[j];
  }
}

// ---------- reduce partials -> v2t (bf16 transposed + ksum row + pad) ------
__global__ __launch_bounds__(256) void k_v2red(
  const float* __restrict__ part, const float* __restrict__ kpart,
  char* __restrict__ wsb)
{
  const int b = blockIdx.y;
  unsigned short* v2t = (unsigned short*)(wsb + V2TB) + b*9216;
  if (blockIdx.x < 32){
    int i = blockIdx.x*256 + threadIdx.x;      // 0..8191 = m*128+d
    const float* p = part + (long)b*196*8192 + i;
    float s = 0.f;
    #pragma unroll 4
    for (int q=0;q<196;q++) s += p[(long)q*8192];
    int m = i >> 7, d = i & 127;
    v2t[d*64 + m] = f2bf(s);
  } else {
    int tidx = threadIdx.x;
    if (tidx < 64){
      const float* p = kpart + (long)b*196*64 + tidx;
      float s = 0.f;
      #pragma unroll 4
      for (int q=0;q<196;q++) s += p[(long)q*64];
      v2t[128*64 + tidx] = f2bf(s);
    }
    for (int j = 129*64 + tidx; j < 144*64; j += 256) v2t[j] = 0;
  }
}

// ---------- attn0 + residual(h0) + LN0 -> h1 -------------------------------
__global__ __launch_bounds__(256, 4) void k_attnln(
  char* __restrict__ wsb, const float* __restrict__ g0,
  const float* __restrict__ bt0)
{
  __shared__ unsigned short ht[64][132];    // 16896 B
  __shared__ unsigned short v2s[144*72];    // 20736 B
  const int b = blockIdx.y;
  const int tid = threadIdx.x;
  const int lane = tid & 63;
  const int w  = tid >> 6;
  const int c  = lane & 15;
  const int kg = lane >> 4;
  const long r0blk = (long)blockIdx.x*64;
  const long r0w = r0blk + w*16;
  const int rrow = tid>>2, rq3 = tid&3;
  const long rgr = r0blk + rrow;
  short8_t aq0, aq1;
  if (r0w + c < NN){
    const unsigned short* qrow = (const unsigned short*)(wsb + QB) + ((long)b*NN + r0w + c)*64 + kg*8;
    aq0 = *(const short8_t*)qrow; aq1 = *(const short8_t*)(qrow + 32);
  } else {
    aq0 = (short8_t){0,0,0,0,0,0,0,0}; aq1 = aq0;
  }
  uint4 rh0={0,0,0,0}, rh1={0,0,0,0}, rh2={0,0,0,0}, rh3={0,0,0,0};
  if (rgr < NN){
    const uint4* hs = (const uint4*)((const unsigned short*)(wsb + H0B) + ((long)b*NN + rgr)*128 + rq3*32);
    rh0=hs[0]; rh1=hs[1]; rh2=hs[2]; rh3=hs[3];
  }
  {
    const uint4* v2g = (const uint4*)((const unsigned short*)(wsb + V2TB) + b*9216);
    #pragma unroll
    for (int e=0;e<5;e++){
      int j = tid + 256*e;
      if (j < 1152){
        int row = j >> 3, cc = j & 7;
        *(uint4*)&v2s[row*72 + cc*8] = v2g[j];
      }
    }
  }
  __syncthreads();
  f32x4 acc[9];
  #pragma unroll
  for (int f=0;f<9;f++) acc[f] = (f32x4){0.f,0.f,0.f,0.f};
  #pragma unroll
  for (int f=0;f<9;f++){
    short8_t b0 = *(const short8_t*)&v2s[(f*16 + c)*72 + kg*8];
    acc[f] = __builtin_amdgcn_mfma_f32_16x16x32_bf16(aq0, b0, acc[f], 0, 0, 0);
    short8_t b1v = *(const short8_t*)&v2s[(f*16 + c)*72 + 32 + kg*8];
    acc[f] = __builtin_amdgcn_mfma_f32_16x16x32_bf16(aq1, b1v, acc[f], 0, 0, 0);
  }
  float inv[4];
  #pragma unroll
  for (int j=0;j<4;j++) inv[j] = 1.0f / __shfl(acc[8][j], (lane & 48));
  #pragma unroll
  for (int f=0;f<8;f++)
    #pragma unroll
    for (int j=0;j<4;j++)
      ht[w*16 + kg*4 + j][f*16 + c] = f2bf(acc[f][j]*inv[j]);
  __syncthreads();
  // row-owner: residual(regs) + LN0 -> h1 (global)
  {
    float tv[32];
    {
      const uint4* os = (const uint4*)&ht[rrow][rq3*32];
      uint4 o0=os[0],o1=os[1],o2=os[2],o3=os[3];
      up8(o0,tv); up8(o1,tv+8); up8(o2,tv+16); up8(o3,tv+24);
    }
    {
      float hv[32];
      up8(rh0,hv); up8(rh1,hv+8); up8(rh2,hv+16); up8(rh3,hv+24);
      #pragma unroll
      for (int i=0;i<32;i++) tv[i] += hv[i];
    }
    float s = 0.f;
    #pragma unroll
    for (int i=0;i<32;i++) s += tv[i];
    s += __shfl_xor(s, 1); s += __shfl_xor(s, 2);
    float mu = s * (1.0f/128.0f);
    float vv = 0.f;
    #pragma unroll
    for (int i=0;i<32;i++){ float e = tv[i]-mu; vv += e*e; }
    vv += __shfl_xor(vv, 1); vv += __shfl_xor(vv, 2);
    float rs = rsqrtf(vv * (1.0f/128.0f) + 1e-5f);
    const float4* gp = (const float4*)(g0 + rq3*32);
    const float4* bp = (const float4*)(bt0 + rq3*32);
    float h1v[32];
    #pragma unroll
    for (int i8=0;i8<8;i8++){
      float4 g4 = gp[i8], b4 = bp[i8];
      h1v[i8*4  ] = (tv[i8*4  ]-mu)*rs*g4.x + b4.x;
      h1v[i8*4+1] = (tv[i8*4+1]-mu)*rs*g4.y + b4.y;
      h1v[i8*4+2] = (tv[i8*4+2]-mu)*rs*g4.z + b4.z;
      h1v[i8*4+3] = (tv[i8*4+3]-mu)*rs*g4.w + b4.w;
    }
    if (rgr < NN){
      uint4 p0=pk8(h1v), p1=pk8(h1v+8), p2=pk8(h1v+16), p3=pk8(h1v+24);
      uint4* dst = (uint4*)((unsigned short*)(wsb + H1B) + ((long)b*NN + rgr)*128 + rq3*32);
      dst[0]=p0; dst[1]=p1; dst[2]=p2; dst[3]=p3;
    }
  }
}

// ---------- attn1 + residual(h1) + LN1 + MFMA regression head --------------
__global__ __launch_bounds__(256) void k_attnhead(
  char* __restrict__ wsb, const float* __restrict__ g1,
  const float* __restrict__ bt1, const float* __restrict__ b_reg,
  float* __restrict__ out)
{
  __shared__ unsigned short ht[64][132];
  __shared__ unsigned short v2s[144*72];    // reused as h0 tile [64][136]
  const int b = blockIdx.y;
  const int tid = threadIdx.x;
  const int lane = tid & 63;
  const int w  = tid >> 6;
  const int c  = lane & 15;
  const int kg = lane >> 4;
  const long r0blk = (long)blockIdx.x*64;
  const long r0w = r0blk + w*16;
  const int rrow = tid>>2, rq3 = tid&3;
  const long rgr = r0blk + rrow;
  short8_t aq0, aq1;
  if (r0w + c < NN){
    const unsigned short* qrow = (const unsigned short*)(wsb + QB) + ((long)b*NN + r0w + c)*64 + kg*8;
    aq0 = *(const short8_t*)qrow; aq1 = *(const short8_t*)(qrow + 32);
  } else {
    aq0 = (short8_t){0,0,0,0,0,0,0,0}; aq1 = aq0;
  }
  uint4 rh0={0,0,0,0}, rh1={0,0,0,0}, rh2={0,0,0,0}, rh3={0,0,0,0};
  uint4 ah0={0,0,0,0}, ah1={0,0,0,0}, ah2={0,0,0,0}, ah3={0,0,0,0};
  if (rgr < NN){
    const uint4* hs = (const uint4*)((const unsigned short*)(wsb + H1B) + ((long)b*NN + rgr)*128 + rq3*32);
    rh0=hs[0]; rh1=hs[1]; rh2=hs[2]; rh3=hs[3];
    const uint4* h0s = (const uint4*)((const unsigned short*)(wsb + H0B) + ((long)b*NN + rgr)*128 + rq3*32);
    ah0=h0s[0]; ah1=h0s[1]; ah2=h0s[2]; ah3=h0s[3];
  }
  {
    const uint4* v2g = (const uint4*)((const unsigned short*)(wsb + V2TB) + b*9216);
    #pragma unroll
    for (int e=0;e<5;e++){
      int j = tid + 256*e;
      if (j < 1152){
        int row = j >> 3, cc = j & 7;
        *(uint4*)&v2s[row*72 + cc*8] = v2g[j];
      }
    }
  }
  __syncthreads();
  f32x4 acc[9];
  #pragma unroll
  for (int f=0;f<9;f++) acc[f] = (f32x4){0.f,0.f,0.f,0.f};
  #pragma unroll
  for (int f=0;f<9;f++){
    short8_t b0 = *(const short8_t*)&v2s[(f*16 + c)*72 + kg*8];
    acc[f] = __builtin_amdgcn_mfma_f32_16x16x32_bf16(aq0, b0, acc[f], 0, 0, 0);
    short8_t b1v = *(const short8_t*)&v2s[(f*16 + c)*72 + 32 + kg*8];
    acc[f] = __builtin_amdgcn_mfma_f32_16x16x32_bf16(aq1, b1v, acc[f], 0, 0, 0);
  }
  float inv[4];
  #pragma unroll
  for (int j=0;j<4;j++) inv[j] = 1.0f / __shfl(acc[8][j], (lane & 48));
  #pragma unroll
  for (int f=0;f<8;f++)
    #pragma unroll
    for (int j=0;j<4;j++)
      ht[w*16 + kg*4 + j][f*16 + c] = f2bf(acc[f][j]*inv[j]);
  __syncthreads();   // v2s reads done -> reuse as h0 tile
  {
    unsigned short* h0t = v2s;
    uint4* hd = (uint4*)&h0t[rrow*136 + rq3*32];
    hd[0]=ah0; hd[1]=ah1; hd[2]=ah2; hd[3]=ah3;
    float tv[32];
    {
      const uint4* os = (const uint4*)&ht[rrow][rq3*32];
      uint4 o0=os[0],o1=os[1],o2=os[2],o3=os[3];
      up8(o0,tv); up8(o1,tv+8); up8(o2,tv+16); up8(o3,tv+24);
    }
    {
      float hv[32];
      up8(rh0,hv); up8(rh1,hv+8); up8(rh2,hv+16); up8(rh3,hv+24);
      #pragma unroll
      for (int i=0;i<32;i++) tv[i] += hv[i];
    }
    float s = 0.f;
    #pragma unroll
    for (int i=0;i<32;i++) s += tv[i];
    s += __shfl_xor(s, 1); s += __shfl_xor(s, 2);
    float mu = s * (1.0f/128.0f);
    float vv = 0.f;
    #pragma unroll
    for (int i=0;i<32;i++){ float e = tv[i]-mu; vv += e*e; }
    vv += __shfl_xor(vv, 1); vv += __shfl_xor(vv, 2);
    float rs = rsqrtf(vv * (1.0f/128.0f) + 1e-5f);
    const float4* gp = (const float4*)(g1 + rq3*32);
    const float4* bp = (const float4*)(bt1 + rq3*32);
    float h2v[32];
    #pragma unroll
    for (int i8=0;i8<8;i8++){
      float4 g4 = gp[i8], b4 = bp[i8];
      h2v[i8*4  ] = fmaxf((tv[i8*4  ]-mu)*rs*g4.x + b4.x, 0.f);
      h2v[i8*4+1] = fmaxf((tv[i8*4+1]-mu)*rs*g4.y + b4.y, 0.f);
      h2v[i8*4+2] = fmaxf((tv[i8*4+2]-mu)*rs*g4.z + b4.z, 0.f);
      h2v[i8*4+3] = fmaxf((tv[i8*4+3]-mu)*rs*g4.w + b4.w, 0.f);
    }
    uint4 p0=pk8(h2v), p1=pk8(h2v+8), p2=pk8(h2v+16), p3=pk8(h2v+24);
    uint4* d = (uint4*)&ht[rrow][rq3*32];
    d[0]=p0; d[1]=p1; d[2]=p2; d[3]=p3;
  }
  __syncthreads();
  const unsigned short* wregT = (const unsigned short*)(wsb + W12B) + 8192;
  const unsigned short* h0t = v2s;
  f32x4 hacc = (f32x4){0.f,0.f,0.f,0.f};
  #pragma unroll
  for (int ks=0;ks<8;ks++){
    short8_t a;
    if (ks < 4)
      a = relu8(*(const short8_t*)&h0t[(w*16 + c)*136 + ks*32 + kg*8]);
    else
      a = *(const short8_t*)&ht[w*16 + c][(ks-4)*32 + kg*8];
    short8_t bb = *(const short8_t*)(wregT + c*256 + ks*32 + kg*8);
    hacc = __builtin_amdgcn_mfma_f32_16x16x32_bf16(a, bb, hacc, 0, 0, 0);
  }
  if (c < 12){
    float br = b_reg[c];
    #pragma unroll
    for (int j=0;j<4;j++){
      long gr = r0w + kg*4 + j;
      if (gr < NN)
        out[((long)b*12 + c)*NN + gr] = hacc[j] + br;
    }
  }
}

extern "C" void kernel_launch(void* const* d_in, const int* in_sizes, int n_in,
                              void* d_out, int out_size, void* d_ws, size_t ws_size,
                              hipStream_t stream)
{
  const float* x        = (const float*)d_in[0];
  const float* node_emb = (const float*)d_in[1];
  const float* time_emb = (const float*)d_in[2];
  const float* week_emb = (const float*)d_in[3];
  const float* W_in     = (const float*)d_in[4];
  const float* b_in     = (const float*)d_in[5];
  const float* W1       = (const float*)d_in[6];
  const float* b1       = (const float*)d_in[7];
  const float* W2       = (const float*)d_in[8];
  const float* b2       = (const float*)d_in[9];
  const float* W_reg    = (const float*)d_in[10];
  const float* b_reg    = (const float*)d_in[11];
  const float* proj     = (const float*)d_in[12];
  const float* fc_in0_w = (const float*)d_in[13];
  const float* fc_in0_b = (const float*)d_in[14];
  const float* fc_out0_w= (const float*)d_in[15];
  const float* fc_out0_b= (const float*)d_in[16];
  const float* ln0_g    = (const float*)d_in[17];
  const float* ln0_b    = (const float*)d_in[18];
  const float* fc_in1_w = (const float*)d_in[19];
  const float* fc_in1_b = (const float*)d_in[20];
  const float* fc_out1_w= (const float*)d_in[21];
  const float* fc_out1_b= (const float*)d_in[22];
  const float* ln1_g    = (const float*)d_in[23];
  const float* ln1_b    = (const float*)d_in[24];
  char* wsb  = (char*)d_ws;
  float* out = (float*)d_out;
  float* part  = (float*)(wsb + PARTB);
  float* kpart = (float*)(wsb + KPARTB);

  dim3 rowgrid((NN+255)/256, NB);     // (196, 4)
  dim3 atngrid(782, NB);              // 782*64 = 50048 >= NN
  dim3 fgrid0(196, NB);               // 196*256 = 50176, 4 tiles/block
  dim3 redgrid(33, NB);

  k_init  <<<1, 256, 0, stream>>>(wsb);
  k_wcvt  <<<256, 256, 0, stream>>>(fc_in0_w, fc_out0_w, fc_in1_w, fc_out1_w, wsb);
  k_wcvt2 <<<48, 256, 0, stream>>>(W1, W2, proj, W_reg, wsb);
  k_pass1a<<<rowgrid, 256, 0, stream>>>(x, node_emb, time_emb, week_emb,
                                        W_in, b_in, wsb);
  k_pass1b<<<atngrid, 256, 0, stream>>>(b1, b2, wsb);
  k_glured<1><<<fgrid0, 256, 0, stream>>>(wsb, (const unsigned short*)(wsb + H0B),
                                          (const unsigned short*)(wsb + WBFB),
                                          fc_in0_b, fc_out0_b, part, kpart);
  k_v2red <<<redgrid, 256, 0, stream>>>(part, kpart, wsb);
  k_attnln<<<atngrid, 256, 0, stream>>>(wsb, ln0_g, ln0_b);
  k_glured<0><<<fgrid0, 256, 0, stream>>>(wsb, (const unsigned short*)(wsb + H1B),
                                          (const unsigned short*)(wsb + WBFB) + 32768,
                                          fc_in1_b, fc_out1_b, part, kpart);
  k_v2red <<<redgrid, 256, 0, stream>>>(part, kpart, wsb);
  k_attnhead<<<atngrid, 256, 0, stream>>>(wsb, ln1_g, ln1_b, b_reg, out);
}

// Round 13
// 496.971 us; speedup vs baseline: 1.6395x; 1.6395x over previous
//
#include <hip/hip_runtime.h>

#define NB 4
#define NN 50000

// ---- workspace byte offsets (total ~154.9 MB, < proven 205.9 MB) ----
#define H0B    0L
#define H1B    51200000L
#define QB     102400000L
#define KKB    128000000L    // k' (unfinalized, bf16)
#define RMB    153600000L    // fp32 rm [4*50000]
#define WBFB   154400000L    // bf16 GLU weights: layer0 [256][128], layer1 at +65536B
#define V2F0B  154531072L    // fp32 v2x layer0 [4][64][128]
#define V2F1B  154662144L    // fp32 v2x layer1
#define KSB    154793216L    // fp32 ksum [4][64]
#define GMB    154794240L    // 4 uints
#define W12B   154795264L    // bf16: W1 [32][96], W2 [32][96], proj [64][32], W_regT [16][256]
#define V2TB   154819840L    // bf16 v2x^T+ksum [4][144][64]
#define NZERO  65796         // words zeroed at V2F0B (v2x0+v2x1+ksum+gmax)

typedef short short8_t __attribute__((ext_vector_type(8)));
typedef float f32x4 __attribute__((ext_vector_type(4)));

__device__ __forceinline__ unsigned short f2bf(float f){
  unsigned u = __float_as_uint(f);
  return (unsigned short)((u + 0x7FFFu + ((u>>16)&1u)) >> 16);
}
__device__ __forceinline__ float bf2f(unsigned short s){
  return __uint_as_float(((unsigned)s)<<16);
}
__device__ __forceinline__ unsigned pk2(float a, float b){
  return (unsigned)f2bf(a) | ((unsigned)f2bf(b)<<16);
}
__device__ __forceinline__ uint4 pk8(const float* f){
  uint4 o; o.x=pk2(f[0],f[1]); o.y=pk2(f[2],f[3]);
  o.z=pk2(f[4],f[5]); o.w=pk2(f[6],f[7]); return o;
}
__device__ __forceinline__ void up8(uint4 v, float* f){
  f[0]=bf2f((unsigned short)(v.x&0xFFFFu)); f[1]=bf2f((unsigned short)(v.x>>16));
  f[2]=bf2f((unsigned short)(v.y&0xFFFFu)); f[3]=bf2f((unsigned short)(v.y>>16));
  f[4]=bf2f((unsigned short)(v.z&0xFFFFu)); f[5]=bf2f((unsigned short)(v.z>>16));
  f[6]=bf2f((unsigned short)(v.w&0xFFFFu)); f[7]=bf2f((unsigned short)(v.w>>16));
}
__device__ __forceinline__ short8_t relu8(short8_t s){
  short8_t r;
  #pragma unroll
  for (int i=0;i<8;i++){ short v = s[i]; r[i] = (v & (short)0x8000) ? (short)0 : v; }
  return r;
}
__device__ __forceinline__ unsigned encOrd(float f){
  unsigned u = __float_as_uint(f);
  return (u & 0x80000000u) ? ~u : (u | 0x80000000u);
}
__device__ __forceinline__ float decOrd(unsigned u){
  return (u & 0x80000000u) ? __uint_as_float(u & 0x7fffffffu)
                           : __uint_as_float(~u);
}

// ---- zero v2x0+v2x1+ksum+gmax ----
__global__ void k_init(char* __restrict__ wsb){
  int i = blockIdx.x*256 + threadIdx.x;
  if (i < NZERO) ((unsigned*)(wsb + V2F0B))[i] = 0u;
}
// ---- GLU weights -> bf16 [n][k] ----
__global__ void k_wcvt(const float* __restrict__ wi0, const float* __restrict__ wo0,
                       const float* __restrict__ wi1, const float* __restrict__ wo1,
                       char* __restrict__ wsb){
  int idx = blockIdx.x*256 + threadIdx.x;
  if (idx >= 65536) return;
  int l = idx >> 15, r = (idx >> 7) & 255, c = idx & 127;
  const float* src = (l==0) ? ((r<128)? wi0 : wo0) : ((r<128)? wi1 : wo1);
  float v = src[(r&127)*128 + c];
  ((unsigned short*)(wsb + WBFB))[l*32768 + r*128 + c] = f2bf(v);
}
// ---- W1,W2 [32][96], proj [64][32], W_regT [16][256] -> bf16 --------------
__global__ void k_wcvt2(const float* __restrict__ W1, const float* __restrict__ W2,
                        const float* __restrict__ proj, const float* __restrict__ W_reg,
                        char* __restrict__ wsb){
  int i = blockIdx.x*256 + threadIdx.x;          // 12288 total
  if (i >= 12288) return;
  unsigned short* dst = (unsigned short*)(wsb + W12B);
  float v;
  if (i < 3072) v = W1[i];
  else if (i < 6144) v = W2[i-3072];
  else if (i < 8192) v = proj[i-6144];
  else {
    int r = (i-8192) >> 8, c = (i-8192) & 255;
    v = (r < 12) ? W_reg[r*256 + c] : 0.f;
  }
  dst[i] = f2bf(v);
}

// ---------- pass1a: h0 (W_in matmul + embeddings) --------------------------
__global__ __launch_bounds__(256) void k_pass1a(
  const float* __restrict__ x, const float* __restrict__ node_emb,
  const float* __restrict__ time_emb, const float* __restrict__ week_emb,
  const float* __restrict__ W_in, const float* __restrict__ b_in,
  char* __restrict__ wsb)
{
  const int b = blockIdx.y;
  const int n = blockIdx.x*256 + threadIdx.x;
  if (n >= NN) return;
  const long row = (long)b*NN + n;
  float xr[36];
  {
    const float4* xp = (const float4*)(x + row*36);
    #pragma unroll
    for (int i=0;i<9;i++){ float4 t=xp[i]; xr[4*i]=t.x; xr[4*i+1]=t.y; xr[4*i+2]=t.z; xr[4*i+3]=t.w; }
  }
  int tidx = (int)(xr[34]*288.0f); tidx = tidx<0?0:(tidx>287?287:tidx);
  int widx = (int)(xr[35]);        widx = widx<0?0:(widx>6?6:widx);
  uint4* h0q = (uint4*)(wsb + H0B) + row*16;
  float hh[32];
  #pragma unroll 1
  for (int jj=0;jj<8;jj++){
    #pragma unroll
    for (int jl=0;jl<4;jl++){
      const int j = jj*4+jl;
      const float* w = W_in + j*36;
      float a0=0.f,a1=0.f,a2=0.f,a3=0.f;
      #pragma unroll
      for (int i=0;i<36;i+=4){ a0+=xr[i]*w[i]; a1+=xr[i+1]*w[i+1]; a2+=xr[i+2]*w[i+2]; a3+=xr[i+3]*w[i+3]; }
      hh[j] = b_in[j] + ((a0+a1)+(a2+a3));
    }
  }
  #pragma unroll
  for (int c=0;c<4;c++) h0q[c] = pk8(hh + 8*c);
  float xg[96];
  {
    const float4* p0 = (const float4*)(node_emb + (long)n*32);
    const float4* p1 = (const float4*)(time_emb + (long)tidx*32);
    const float4* p2 = (const float4*)(week_emb + (long)widx*32);
    #pragma unroll
    for (int i=0;i<8;i++){ float4 t=p0[i]; xg[4*i]=t.x; xg[4*i+1]=t.y; xg[4*i+2]=t.z; xg[4*i+3]=t.w; }
    #pragma unroll
    for (int i=0;i<8;i++){ float4 t=p1[i]; xg[32+4*i]=t.x; xg[32+4*i+1]=t.y; xg[32+4*i+2]=t.z; xg[32+4*i+3]=t.w; }
    #pragma unroll
    for (int i=0;i<8;i++){ float4 t=p2[i]; xg[64+4*i]=t.x; xg[64+4*i+1]=t.y; xg[64+4*i+2]=t.z; xg[64+4*i+3]=t.w; }
  }
  #pragma unroll
  for (int c=0;c<12;c++) h0q[4+c] = pk8(xg + 8*c);
}

// ---------- pass1b (MFMA): q, k', rm, global key max -----------------------
__global__ __launch_bounds__(256) void k_pass1b(
  const float* __restrict__ b1, const float* __restrict__ b2,
  char* __restrict__ wsb)
{
  __shared__ unsigned short xgt[64][104];
  __shared__ unsigned short dt[2][64][40];
  __shared__ unsigned short ot[64][72];
  __shared__ float wred[4];
  const int b   = blockIdx.y;
  const int tid = threadIdx.x;
  const int lane= tid & 63;
  const int w   = tid >> 6;
  const int c   = lane & 15;
  const int kg  = lane >> 4;
  const long r0blk = (long)blockIdx.x * 64;
  {
    int row = tid >> 2, q3 = tid & 3;
    long gr = r0blk + row;
    uint4 v0={0,0,0,0}, v1=v0, v2=v0;
    if (gr < NN){
      const uint4* src = (const uint4*)(wsb + H0B + ((long)b*NN + gr)*256 + 64 + q3*48);
      v0=src[0]; v1=src[1]; v2=src[2];
    }
    uint4* d = (uint4*)&xgt[row][q3*24];
    d[0]=v0; d[1]=v1; d[2]=v2;
  }
  __syncthreads();
  const unsigned short* w1bf = (const unsigned short*)(wsb + W12B);
  const unsigned short* w2bf = w1bf + 3072;
  const unsigned short* pjbf = w1bf + 6144;
  f32x4 accd[2][2];
  #pragma unroll
  for (int s=0;s<2;s++)
    #pragma unroll
    for (int f=0;f<2;f++) accd[s][f] = (f32x4){0.f,0.f,0.f,0.f};
  #pragma unroll
  for (int ks=0;ks<3;ks++){
    short8_t a = *(const short8_t*)&xgt[w*16 + c][ks*32 + kg*8];
    #pragma unroll
    for (int f=0;f<2;f++){
      short8_t bw1 = *(const short8_t*)(w1bf + (f*16+c)*96 + ks*32 + kg*8);
      accd[0][f] = __builtin_amdgcn_mfma_f32_16x16x32_bf16(a, bw1, accd[0][f], 0,0,0);
      short8_t bw2 = *(const short8_t*)(w2bf + (f*16+c)*96 + ks*32 + kg*8);
      accd[1][f] = __builtin_amdgcn_mfma_f32_16x16x32_bf16(a, bw2, accd[1][f], 0,0,0);
    }
  }
  const float DSC = 0.42044820762685725f;   // 32^-0.25
  float dv[2][2][4];
  #pragma unroll
  for (int f=0;f<2;f++){
    float bb1 = b1[f*16+c], bb2 = b2[f*16+c];
    #pragma unroll
    for (int jj=0;jj<4;jj++){
      dv[0][f][jj] = (accd[0][f][jj] + bb1) * DSC;
      dv[1][f][jj] = (accd[1][f][jj] + bb2) * DSC;
    }
  }
  float dg[2][4];
  #pragma unroll
  for (int s=0;s<2;s++)
    #pragma unroll
    for (int jj=0;jj<4;jj++){
      float t = dv[s][0][jj]*dv[s][0][jj] + dv[s][1][jj]*dv[s][1][jj];
      #pragma unroll
      for (int off=1; off<16; off<<=1) t += __shfl_xor(t, off);
      dg[s][jj] = 0.5f * t;
    }
  #pragma unroll
  for (int s=0;s<2;s++)
    #pragma unroll
    for (int f=0;f<2;f++)
      #pragma unroll
      for (int jj=0;jj<4;jj++)
        dt[s][w*16 + kg*4 + jj][f*16 + c] = f2bf(dv[s][f][jj]);
  __syncthreads();
  f32x4 acc2[2][4];
  #pragma unroll
  for (int s=0;s<2;s++){
    short8_t ad = *(const short8_t*)&dt[s][w*16 + c][kg*8];
    #pragma unroll
    for (int f=0;f<4;f++){
      short8_t bp = *(const short8_t*)(pjbf + (f*16+c)*32 + kg*8);
      acc2[s][f] = __builtin_amdgcn_mfma_f32_16x16x32_bf16(ad, bp, (f32x4){0.f,0.f,0.f,0.f}, 0,0,0);
    }
  }
  float mx[2][4];
  #pragma unroll
  for (int s=0;s<2;s++)
    #pragma unroll
    for (int jj=0;jj<4;jj++){
      float t = fmaxf(fmaxf(acc2[s][0][jj],acc2[s][1][jj]),
                      fmaxf(acc2[s][2][jj],acc2[s][3][jj]));
      #pragma unroll
      for (int off=1; off<16; off<<=1) t = fmaxf(t, __shfl_xor(t, off));
      mx[s][jj] = t;
    }
  #pragma unroll
  for (int f=0;f<4;f++)
    #pragma unroll
    for (int jj=0;jj<4;jj++){
      float qv = 0.125f*(__expf(acc2[0][f][jj] - dg[0][jj] - mx[0][jj]) + 1e-6f);
      ot[w*16 + kg*4 + jj][f*16 + c] = f2bf(qv);
    }
  __syncthreads();
  {
    int row = tid >> 2, q3 = tid & 3;
    long gr = r0blk + row;
    if (gr < NN){
      const uint4* s = (const uint4*)&ot[row][q3*16];
      uint4* dst = (uint4*)((unsigned short*)(wsb + QB) + ((long)b*NN + gr)*64 + q3*16);
      dst[0] = s[0]; dst[1] = s[1];
    }
  }
  __syncthreads();
  float bmax = -3.0e38f;
  #pragma unroll
  for (int f=0;f<4;f++)
    #pragma unroll
    for (int jj=0;jj<4;jj++){
      float kv = __expf(acc2[1][f][jj] - mx[1][jj]);
      ot[w*16 + kg*4 + jj][f*16 + c] = f2bf(kv);
    }
  #pragma unroll
  for (int jj=0;jj<4;jj++){
    long gr = r0blk + w*16 + kg*4 + jj;
    bool val = (gr < NN);
    if (val && c==0)
      ((float*)(wsb + RMB))[(long)b*NN + gr] = mx[1][jj] - dg[1][jj];
    if (val) bmax = fmaxf(bmax, mx[1][jj]);
  }
  #pragma unroll
  for (int off=32; off>0; off>>=1) bmax = fmaxf(bmax, __shfl_xor(bmax, off));
  if (lane==0) wred[w] = bmax;
  __syncthreads();
  {
    int row = tid >> 2, q3 = tid & 3;
    long gr = r0blk + row;
    if (gr < NN){
      const uint4* s = (const uint4*)&ot[row][q3*16];
      uint4* dst = (uint4*)((unsigned short*)(wsb + KKB) + ((long)b*NN + gr)*64 + q3*16);
      dst[0] = s[0]; dst[1] = s[1];
    }
  }
  if (tid==0){
    float m2 = fmaxf(fmaxf(wred[0],wred[1]), fmaxf(wred[2],wred[3]));
    atomicMax((unsigned*)(wsb + GMB) + b, encOrd(m2));
  }
}

// ---------- fused GLU + k-finalize (+ksum) + MFMA reduce (round-7 shape) ---
__global__ __launch_bounds__(256) void k_glured(
  char* __restrict__ wsb, const unsigned short* __restrict__ hsrc,
  const unsigned short* __restrict__ wbf,
  const float* __restrict__ bi, const float* __restrict__ bo,
  float* __restrict__ v2x_out, float* __restrict__ ksout)
{
  __shared__ unsigned short pool[9216];        // ht[64][136] alias htT[128][72]
  __shared__ unsigned short ktl[64][72];       // finalized k^T [m][n]
  __shared__ float red[256];
  unsigned short (*ht)[136] = (unsigned short(*)[136])pool;
  unsigned short (*htT)[72] = (unsigned short(*)[72])pool;
  const int b = blockIdx.y;
  const int tid = threadIdx.x;
  const int lane = tid & 63;
  const int w = tid >> 6;
  const int c = lane & 15;
  const int kg = lane >> 4;
  const float gm = decOrd(((const unsigned*)(wsb + GMB))[b]);
  const float* rm = (const float*)(wsb + RMB) + (long)b*NN;
  const uint4* kbase = (const uint4*)(wsb + KKB) + (long)b*NN*8;
  f32x4 racc[8];
  #pragma unroll
  for (int f=0;f<8;f++) racc[f] = (f32x4){0.f,0.f,0.f,0.f};
  float ksacc = 0.f;
  float bi_l[8], bo_l[8];
  #pragma unroll
  for (int f=0;f<8;f++){ bi_l[f] = bi[f*16+c]; bo_l[f] = bo[f*16+c]; }
  #pragma unroll 1
  for (int t=0;t<4;t++){
    const long r0 = (long)blockIdx.x*256 + t*64;
    { // stage h tile
      int row = tid>>2, q3 = tid&3;
      long gr = r0 + row;
      uint4 v0={0,0,0,0},v1=v0,v2=v0,v3=v0;
      if (gr < NN){
        const uint4* src = (const uint4*)(hsrc + ((long)b*NN + gr)*128 + q3*32);
        v0=src[0]; v1=src[1]; v2=src[2]; v3=src[3];
      }
      uint4* d = (uint4*)&ht[row][q3*32];
      d[0]=v0; d[1]=v1; d[2]=v2; d[3]=v3;
    }
    // stage finalized k^T
    #pragma unroll
    for (int e=0;e<2;e++){
      int f = tid + 256*e;
      int rr = f>>3, cc = f&7;
      long gr = r0 + rr;
      float tv[8];
      if (gr < NN){
        uint4 raw = kbase[gr*8 + cc];
        float scale = __expf(rm[gr] - gm);
        up8(raw, tv);
        #pragma unroll
        for (int i=0;i<8;i++) tv[i] = 0.125f*(tv[i]*scale + 1e-6f);
      } else {
        #pragma unroll
        for (int i=0;i<8;i++) tv[i] = 0.f;
      }
      #pragma unroll
      for (int i=0;i<8;i++) ktl[cc*8+i][rr] = f2bf(tv[i]);
    }
    __syncthreads();
    // GLU0 MFMA (full gacc[16] — empirically fastest allocation)
    f32x4 gacc[16];
    #pragma unroll
    for (int f=0;f<16;f++) gacc[f] = (f32x4){0.f,0.f,0.f,0.f};
    #pragma unroll
    for (int ks=0;ks<4;ks++){
      short8_t a = *(const short8_t*)&ht[w*16 + c][ks*32 + kg*8];
      #pragma unroll
      for (int f=0;f<16;f++){
        short8_t bb = *(const short8_t*)(wbf + (f*16 + c)*128 + ks*32 + kg*8);
        gacc[f] = __builtin_amdgcn_mfma_f32_16x16x32_bf16(a, bb, gacc[f], 0, 0, 0);
      }
    }
    float ov[8][4];
    #pragma unroll
    for (int f=0;f<8;f++)
      #pragma unroll
      for (int j=0;j<4;j++){
        float aa = gacc[f][j]   + bi_l[f];
        float cc2= gacc[f+8][j] + bo_l[f];
        ov[f][j] = cc2 / (1.0f + __expf(-aa));
      }
    if (ksout){ // ksum partial from ktl
      int m = tid & 63, n0 = (tid>>6)*16;
      #pragma unroll
      for (int n=0;n<16;n++) ksacc += bf2f(ktl[m][n0+n]);
    }
    __syncthreads();   // ht reads done (htT aliases)
    // write v transposed (zero OOB rows)
    #pragma unroll
    for (int f=0;f<8;f++)
      #pragma unroll
      for (int j=0;j<4;j++){
        bool val = (r0 + w*16 + kg*4 + j) < NN;
        htT[f*16 + c][w*16 + kg*4 + j] = val ? f2bf(ov[f][j]) : (unsigned short)0;
      }
    __syncthreads();
    // reduce MFMA: wave w -> out rows m = w*16..+15
    #pragma unroll
    for (int ks=0;ks<2;ks++){
      short8_t a = *(const short8_t*)&ktl[w*16 + c][ks*32 + kg*8];
      #pragma unroll
      for (int f=0;f<8;f++){
        short8_t bb = *(const short8_t*)&htT[f*16 + c][ks*32 + kg*8];
        racc[f] = __builtin_amdgcn_mfma_f32_16x16x32_bf16(a, bb, racc[f], 0, 0, 0);
      }
    }
    __syncthreads();   // loop-end WAR
  }
  float* v2x = v2x_out + (long)b*8192;
  #pragma unroll
  for (int f=0;f<8;f++)
    #pragma unroll
    for (int j=0;j<4;j++)
      atomicAdd(&v2x[(w*16 + kg*4 + j)*128 + f*16 + c], racc[f][j]);
  if (ksout){
    red[tid] = ksacc;
    __syncthreads();
    if (tid < 64)
      atomicAdd(ksout + b*64 + tid,
                red[tid]+red[64+tid]+red[128+tid]+red[192+tid]);
  }
}

// ---------- v2t[b][n][m]: n<128: v2x[m][n]; n=128: ksum[m]; n>128: 0 -------
__global__ void k_v2cvt(char* __restrict__ wsb, const float* __restrict__ v2f){
  int idx = blockIdx.x*256 + threadIdx.x;          // 36864
  if (idx >= 36864) return;
  int b = idx / 9216, rem = idx % 9216;
  int n = rem / 64, m = rem % 64;
  const float* ks = (const float*)(wsb + KSB);
  float v = (n < 128) ? v2f[b*8192 + m*128 + n] : ((n==128) ? ks[b*64+m] : 0.f);
  ((unsigned short*)(wsb + V2TB))[b*9216 + n*64 + m] = f2bf(v);
}

// ---------- attn0 + residual(h0) + LN0 -> h1 -------------------------------
__global__ __launch_bounds__(256, 4) void k_attnln(
  char* __restrict__ wsb, const float* __restrict__ g0,
  const float* __restrict__ bt0)
{
  __shared__ unsigned short ht[64][132];    // 16896 B
  __shared__ unsigned short v2s[144*72];    // 20736 B
  const int b = blockIdx.y;
  const int tid = threadIdx.x;
  const int lane = tid & 63;
  const int w  = tid >> 6;
  const int c  = lane & 15;
  const int kg = lane >> 4;
  const long r0blk = (long)blockIdx.x*64;
  const long r0w = r0blk + w*16;
  const int rrow = tid>>2, rq3 = tid&3;
  const long rgr = r0blk + rrow;
  short8_t aq0, aq1;
  if (r0w + c < NN){
    const unsigned short* qrow = (const unsigned short*)(wsb + QB) + ((long)b*NN + r0w + c)*64 + kg*8;
    aq0 = *(const short8_t*)qrow; aq1 = *(const short8_t*)(qrow + 32);
  } else {
    aq0 = (short8_t){0,0,0,0,0,0,0,0}; aq1 = aq0;
  }
  uint4 rh0={0,0,0,0}, rh1={0,0,0,0}, rh2={0,0,0,0}, rh3={0,0,0,0};
  if (rgr < NN){
    const uint4* hs = (const uint4*)((const unsigned short*)(wsb + H0B) + ((long)b*NN + rgr)*128 + rq3*32);
    rh0=hs[0]; rh1=hs[1]; rh2=hs[2]; rh3=hs[3];
  }
  {
    const uint4* v2g = (const uint4*)((const unsigned short*)(wsb + V2TB) + b*9216);
    #pragma unroll
    for (int e=0;e<5;e++){
      int j = tid + 256*e;
      if (j < 1152){
        int row = j >> 3, cc = j & 7;
        *(uint4*)&v2s[row*72 + cc*8] = v2g[j];
      }
    }
  }
  __syncthreads();
  f32x4 acc[9];
  #pragma unroll
  for (int f=0;f<9;f++) acc[f] = (f32x4){0.f,0.f,0.f,0.f};
  #pragma unroll
  for (int f=0;f<9;f++){
    short8_t b0 = *(const short8_t*)&v2s[(f*16 + c)*72 + kg*8];
    acc[f] = __builtin_amdgcn_mfma_f32_16x16x32_bf16(aq0, b0, acc[f], 0, 0, 0);
    short8_t b1v = *(const short8_t*)&v2s[(f*16 + c)*72 + 32 + kg*8];
    acc[f] = __builtin_amdgcn_mfma_f32_16x16x32_bf16(aq1, b1v, acc[f], 0, 0, 0);
  }
  float inv[4];
  #pragma unroll
  for (int j=0;j<4;j++) inv[j] = 1.0f / __shfl(acc[8][j], (lane & 48));
  #pragma unroll
  for (int f=0;f<8;f++)
    #pragma unroll
    for (int j=0;j<4;j++)
      ht[w*16 + kg*4 + j][f*16 + c] = f2bf(acc[f][j]*inv[j]);
  __syncthreads();
  // row-owner: residual(regs) + LN0 -> h1 (global)
  {
    float tv[32];
    {
      const uint4* os = (const uint4*)&ht[rrow][rq3*32];
      uint4 o0=os[0],o1=os[1],o2=os[2],o3=os[3];
      up8(o0,tv); up8(o1,tv+8); up8(o2,tv+16); up8(o3,tv+24);
    }
    {
      float hv[32];
      up8(rh0,hv); up8(rh1,hv+8); up8(rh2,hv+16); up8(rh3,hv+24);
      #pragma unroll
      for (int i=0;i<32;i++) tv[i] += hv[i];
    }
    float s = 0.f;
    #pragma unroll
    for (int i=0;i<32;i++) s += tv[i];
    s += __shfl_xor(s, 1); s += __shfl_xor(s, 2);
    float mu = s * (1.0f/128.0f);
    float vv = 0.f;
    #pragma unroll
    for (int i=0;i<32;i++){ float e = tv[i]-mu; vv += e*e; }
    vv += __shfl_xor(vv, 1); vv += __shfl_xor(vv, 2);
    float rs = rsqrtf(vv * (1.0f/128.0f) + 1e-5f);
    const float4* gp = (const float4*)(g0 + rq3*32);
    const float4* bp = (const float4*)(bt0 + rq3*32);
    float h1v[32];
    #pragma unroll
    for (int i8=0;i8<8;i8++){
      float4 g4 = gp[i8], b4 = bp[i8];
      h1v[i8*4  ] = (tv[i8*4  ]-mu)*rs*g4.x + b4.x;
      h1v[i8*4+1] = (tv[i8*4+1]-mu)*rs*g4.y + b4.y;
      h1v[i8*4+2] = (tv[i8*4+2]-mu)*rs*g4.z + b4.z;
      h1v[i8*4+3] = (tv[i8*4+3]-mu)*rs*g4.w + b4.w;
    }
    if (rgr < NN){
      uint4 p0=pk8(h1v), p1=pk8(h1v+8), p2=pk8(h1v+16), p3=pk8(h1v+24);
      uint4* dst = (uint4*)((unsigned short*)(wsb + H1B) + ((long)b*NN + rgr)*128 + rq3*32);
      dst[0]=p0; dst[1]=p1; dst[2]=p2; dst[3]=p3;
    }
  }
}

// ---------- attn1 + residual(h1) + LN1 + MFMA regression head --------------
__global__ __launch_bounds__(256) void k_attnhead(
  char* __restrict__ wsb, const float* __restrict__ g1,
  const float* __restrict__ bt1, const float* __restrict__ b_reg,
  float* __restrict__ out)
{
  __shared__ unsigned short ht[64][132];
  __shared__ unsigned short v2s[144*72];    // reused as h0 tile [64][136]
  const int b = blockIdx.y;
  const int tid = threadIdx.x;
  const int lane = tid & 63;
  const int w  = tid >> 6;
  const int c  = lane & 15;
  const int kg = lane >> 4;
  const long r0blk = (long)blockIdx.x*64;
  const long r0w = r0blk + w*16;
  const int rrow = tid>>2, rq3 = tid&3;
  const long rgr = r0blk + rrow;
  short8_t aq0, aq1;
  if (r0w + c < NN){
    const unsigned short* qrow = (const unsigned short*)(wsb + QB) + ((long)b*NN + r0w + c)*64 + kg*8;
    aq0 = *(const short8_t*)qrow; aq1 = *(const short8_t*)(qrow + 32);
  } else {
    aq0 = (short8_t){0,0,0,0,0,0,0,0}; aq1 = aq0;
  }
  uint4 rh0={0,0,0,0}, rh1={0,0,0,0}, rh2={0,0,0,0}, rh3={0,0,0,0};
  uint4 ah0={0,0,0,0}, ah1={0,0,0,0}, ah2={0,0,0,0}, ah3={0,0,0,0};
  if (rgr < NN){
    const uint4* hs = (const uint4*)((const unsigned short*)(wsb + H1B) + ((long)b*NN + rgr)*128 + rq3*32);
    rh0=hs[0]; rh1=hs[1]; rh2=hs[2]; rh3=hs[3];
    const uint4* h0s = (const uint4*)((const unsigned short*)(wsb + H0B) + ((long)b*NN + rgr)*128 + rq3*32);
    ah0=h0s[0]; ah1=h0s[1]; ah2=h0s[2]; ah3=h0s[3];
  }
  {
    const uint4* v2g = (const uint4*)((const unsigned short*)(wsb + V2TB) + b*9216);
    #pragma unroll
    for (int e=0;e<5;e++){
      int j = tid + 256*e;
      if (j < 1152){
        int row = j >> 3, cc = j & 7;
        *(uint4*)&v2s[row*72 + cc*8] = v2g[j];
      }
    }
  }
  __syncthreads();
  f32x4 acc[9];
  #pragma unroll
  for (int f=0;f<9;f++) acc[f] = (f32x4){0.f,0.f,0.f,0.f};
  #pragma unroll
  for (int f=0;f<9;f++){
    short8_t b0 = *(const short8_t*)&v2s[(f*16 + c)*72 + kg*8];
    acc[f] = __builtin_amdgcn_mfma_f32_16x16x32_bf16(aq0, b0, acc[f], 0, 0, 0);
    short8_t b1v = *(const short8_t*)&v2s[(f*16 + c)*72 + 32 + kg*8];
    acc[f] = __builtin_amdgcn_mfma_f32_16x16x32_bf16(aq1, b1v, acc[f], 0, 0, 0);
  }
  float inv[4];
  #pragma unroll
  for (int j=0;j<4;j++) inv[j] = 1.0f / __shfl(acc[8][j], (lane & 48));
  #pragma unroll
  for (int f=0;f<8;f++)
    #pragma unroll
    for (int j=0;j<4;j++)
      ht[w*16 + kg*4 + j][f*16 + c] = f2bf(acc[f][j]*inv[j]);
  __syncthreads();   // v2s reads done -> reuse as h0 tile
  {
    unsigned short* h0t = v2s;
    uint4* hd = (uint4*)&h0t[rrow*136 + rq3*32];
    hd[0]=ah0; hd[1]=ah1; hd[2]=ah2; hd[3]=ah3;
    float tv[32];
    {
      const uint4* os = (const uint4*)&ht[rrow][rq3*32];
      uint4 o0=os[0],o1=os[1],o2=os[2],o3=os[3];
      up8(o0,tv); up8(o1,tv+8); up8(o2,tv+16); up8(o3,tv+24);
    }
    {
      float hv[32];
      up8(rh0,hv); up8(rh1,hv+8); up8(rh2,hv+16); up8(rh3,hv+24);
      #pragma unroll
      for (int i=0;i<32;i++) tv[i] += hv[i];
    }
    float s = 0.f;
    #pragma unroll
    for (int i=0;i<32;i++) s += tv[i];
    s += __shfl_xor(s, 1); s += __shfl_xor(s, 2);
    float mu = s * (1.0f/128.0f);
    float vv = 0.f;
    #pragma unroll
    for (int i=0;i<32;i++){ float e = tv[i]-mu; vv += e*e; }
    vv += __shfl_xor(vv, 1); vv += __shfl_xor(vv, 2);
    float rs = rsqrtf(vv * (1.0f/128.0f) + 1e-5f);
    const float4* gp = (const float4*)(g1 + rq3*32);
    const float4* bp = (const float4*)(bt1 + rq3*32);
    float h2v[32];
    #pragma unroll
    for (int i8=0;i8<8;i8++){
      float4 g4 = gp[i8], b4 = bp[i8];
      h2v[i8*4  ] = fmaxf((tv[i8*4  ]-mu)*rs*g4.x + b4.x, 0.f);
      h2v[i8*4+1] = fmaxf((tv[i8*4+1]-mu)*rs*g4.y + b4.y, 0.f);
      h2v[i8*4+2] = fmaxf((tv[i8*4+2]-mu)*rs*g4.z + b4.z, 0.f);
      h2v[i8*4+3] = fmaxf((tv[i8*4+3]-mu)*rs*g4.w + b4.w, 0.f);
    }
    uint4 p0=pk8(h2v), p1=pk8(h2v+8), p2=pk8(h2v+16), p3=pk8(h2v+24);
    uint4* d = (uint4*)&ht[rrow][rq3*32];
    d[0]=p0; d[1]=p1; d[2]=p2; d[3]=p3;
  }
  __syncthreads();
  const unsigned short* wregT = (const unsigned short*)(wsb + W12B) + 8192;
  const unsigned short* h0t = v2s;
  f32x4 hacc = (f32x4){0.f,0.f,0.f,0.f};
  #pragma unroll
  for (int ks=0;ks<8;ks++){
    short8_t a;
    if (ks < 4)
      a = relu8(*(const short8_t*)&h0t[(w*16 + c)*136 + ks*32 + kg*8]);
    else
      a = *(const short8_t*)&ht[w*16 + c][(ks-4)*32 + kg*8];
    short8_t bb = *(const short8_t*)(wregT + c*256 + ks*32 + kg*8);
    hacc = __builtin_amdgcn_mfma_f32_16x16x32_bf16(a, bb, hacc, 0, 0, 0);
  }
  if (c < 12){
    float br = b_reg[c];
    #pragma unroll
    for (int j=0;j<4;j++){
      long gr = r0w + kg*4 + j;
      if (gr < NN)
        out[((long)b*12 + c)*NN + gr] = hacc[j] + br;
    }
  }
}

extern "C" void kernel_launch(void* const* d_in, const int* in_sizes, int n_in,
                              void* d_out, int out_size, void* d_ws, size_t ws_size,
                              hipStream_t stream)
{
  const float* x        = (const float*)d_in[0];
  const float* node_emb = (const float*)d_in[1];
  const float* time_emb = (const float*)d_in[2];
  const float* week_emb = (const float*)d_in[3];
  const float* W_in     = (const float*)d_in[4];
  const float* b_in     = (const float*)d_in[5];
  const float* W1       = (const float*)d_in[6];
  const float* b1       = (const float*)d_in[7];
  const float* W2       = (const float*)d_in[8];
  const float* b2       = (const float*)d_in[9];
  const float* W_reg    = (const float*)d_in[10];
  const float* b_reg    = (const float*)d_in[11];
  const float* proj     = (const float*)d_in[12];
  const float* fc_in0_w = (const float*)d_in[13];
  const float* fc_in0_b = (const float*)d_in[14];
  const float* fc_out0_w= (const float*)d_in[15];
  const float* fc_out0_b= (const float*)d_in[16];
  const float* ln0_g    = (const float*)d_in[17];
  const float* ln0_b    = (const float*)d_in[18];
  const float* fc_in1_w = (const float*)d_in[19];
  const float* fc_in1_b = (const float*)d_in[20];
  const float* fc_out1_w= (const float*)d_in[21];
  const float* fc_out1_b= (const float*)d_in[22];
  const float* ln1_g    = (const float*)d_in[23];
  const float* ln1_b    = (const float*)d_in[24];
  char* wsb  = (char*)d_ws;
  float* out = (float*)d_out;

  dim3 rowgrid((NN+255)/256, NB);     // (196, 4)
  dim3 atngrid(782, NB);              // 782*64 = 50048 >= NN
  dim3 fgrid0(196, NB);               // 196*256 = 50176, 4 tiles/block
  dim3 cvtgrid(144);

  k_init  <<<258, 256, 0, stream>>>(wsb);
  k_wcvt  <<<256, 256, 0, stream>>>(fc_in0_w, fc_out0_w, fc_in1_w, fc_out1_w, wsb);
  k_wcvt2 <<<48, 256, 0, stream>>>(W1, W2, proj, W_reg, wsb);
  k_pass1a<<<rowgrid, 256, 0, stream>>>(x, node_emb, time_emb, week_emb,
                                        W_in, b_in, wsb);
  k_pass1b<<<atngrid, 256, 0, stream>>>(b1, b2, wsb);
  k_glured<<<fgrid0, 256, 0, stream>>>(wsb, (const unsigned short*)(wsb + H0B),
                                       (const unsigned short*)(wsb + WBFB),
                                       fc_in0_b, fc_out0_b,
                                       (float*)(wsb + V2F0B), (float*)(wsb + KSB));
  k_v2cvt <<<cvtgrid, 256, 0, stream>>>(wsb, (const float*)(wsb + V2F0B));
  k_attnln<<<atngrid, 256, 0, stream>>>(wsb, ln0_g, ln0_b);
  k_glured<<<fgrid0, 256, 0, stream>>>(wsb, (const unsigned short*)(wsb + H1B),
                                       (const unsigned short*)(wsb + WBFB) + 32768,
                                       fc_in1_b, fc_out1_b,
                                       (float*)(wsb + V2F1B), (float*)nullptr);
  k_v2cvt <<<cvtgrid, 256, 0, stream>>>(wsb, (const float*)(wsb + V2F1B));
  k_attnhead<<<atngrid, 256, 0, stream>>>(wsb, ln1_g, ln1_b, b_reg, out);
}

// Round 14
// 465.583 us; speedup vs baseline: 1.7501x; 1.0674x over previous
//
#include <hip/hip_runtime.h>

#define NB 4
#define NN 50000

// ---- workspace byte offsets (total ~154.9 MB, < proven 205.9 MB) ----
#define H0B    0L
#define H1B    51200000L
#define QB     102400000L
#define KKB    128000000L    // k' (unfinalized, bf16)
#define RMB    153600000L    // fp32 rm [4*50000]
#define WBFB   154400000L    // bf16 GLU weights: layer0 [256][128], layer1 at +65536B
#define V2F0B  154531072L    // fp32 v2x layer0 [4][64][128]
#define V2F1B  154662144L    // fp32 v2x layer1
#define KSB    154793216L    // fp32 ksum [4][64]
#define GMB    154794240L    // 4 uints
#define W12B   154795264L    // bf16: W1 [32][96], W2 [32][96], proj [64][32], W_regT [16][256]
#define V2TB   154819840L    // bf16 v2x^T+ksum [4][144][64]
#define NZERO  65796         // words zeroed at V2F0B (v2x0+v2x1+ksum+gmax)

typedef short short8_t __attribute__((ext_vector_type(8)));
typedef float f32x4 __attribute__((ext_vector_type(4)));

__device__ __forceinline__ unsigned short f2bf(float f){
  unsigned u = __float_as_uint(f);
  return (unsigned short)((u + 0x7FFFu + ((u>>16)&1u)) >> 16);
}
__device__ __forceinline__ float bf2f(unsigned short s){
  return __uint_as_float(((unsigned)s)<<16);
}
__device__ __forceinline__ unsigned pk2(float a, float b){
  return (unsigned)f2bf(a) | ((unsigned)f2bf(b)<<16);
}
__device__ __forceinline__ uint4 pk8(const float* f){
  uint4 o; o.x=pk2(f[0],f[1]); o.y=pk2(f[2],f[3]);
  o.z=pk2(f[4],f[5]); o.w=pk2(f[6],f[7]); return o;
}
__device__ __forceinline__ void up8(uint4 v, float* f){
  f[0]=bf2f((unsigned short)(v.x&0xFFFFu)); f[1]=bf2f((unsigned short)(v.x>>16));
  f[2]=bf2f((unsigned short)(v.y&0xFFFFu)); f[3]=bf2f((unsigned short)(v.y>>16));
  f[4]=bf2f((unsigned short)(v.z&0xFFFFu)); f[5]=bf2f((unsigned short)(v.z>>16));
  f[6]=bf2f((unsigned short)(v.w&0xFFFFu)); f[7]=bf2f((unsigned short)(v.w>>16));
}
__device__ __forceinline__ short8_t relu8(short8_t s){
  short8_t r;
  #pragma unroll
  for (int i=0;i<8;i++){ short v = s[i]; r[i] = (v & (short)0x8000) ? (short)0 : v; }
  return r;
}
__device__ __forceinline__ unsigned encOrd(float f){
  unsigned u = __float_as_uint(f);
  return (u & 0x80000000u) ? ~u : (u | 0x80000000u);
}
__device__ __forceinline__ float decOrd(unsigned u){
  return (u & 0x80000000u) ? __uint_as_float(u & 0x7fffffffu)
                           : __uint_as_float(~u);
}

// ---- zero v2x0+v2x1+ksum+gmax ----
__global__ void k_init(char* __restrict__ wsb){
  int i = blockIdx.x*256 + threadIdx.x;
  if (i < NZERO) ((unsigned*)(wsb + V2F0B))[i] = 0u;
}
// ---- GLU weights -> bf16 [n][k] ----
__global__ void k_wcvt(const float* __restrict__ wi0, const float* __restrict__ wo0,
                       const float* __restrict__ wi1, const float* __restrict__ wo1,
                       char* __restrict__ wsb){
  int idx = blockIdx.x*256 + threadIdx.x;
  if (idx >= 65536) return;
  int l = idx >> 15, r = (idx >> 7) & 255, c = idx & 127;
  const float* src = (l==0) ? ((r<128)? wi0 : wo0) : ((r<128)? wi1 : wo1);
  float v = src[(r&127)*128 + c];
  ((unsigned short*)(wsb + WBFB))[l*32768 + r*128 + c] = f2bf(v);
}
// ---- W1,W2 [32][96], proj [64][32], W_regT [16][256] -> bf16 --------------
__global__ void k_wcvt2(const float* __restrict__ W1, const float* __restrict__ W2,
                        const float* __restrict__ proj, const float* __restrict__ W_reg,
                        char* __restrict__ wsb){
  int i = blockIdx.x*256 + threadIdx.x;          // 12288 total
  if (i >= 12288) return;
  unsigned short* dst = (unsigned short*)(wsb + W12B);
  float v;
  if (i < 3072) v = W1[i];
  else if (i < 6144) v = W2[i-3072];
  else if (i < 8192) v = proj[i-6144];
  else {
    int r = (i-8192) >> 8, c = (i-8192) & 255;
    v = (r < 12) ? W_reg[r*256 + c] : 0.f;
  }
  dst[i] = f2bf(v);
}

// ---------- pass1a: h0 (W_in matmul + embeddings) --------------------------
__global__ __launch_bounds__(256) void k_pass1a(
  const float* __restrict__ x, const float* __restrict__ node_emb,
  const float* __restrict__ time_emb, const float* __restrict__ week_emb,
  const float* __restrict__ W_in, const float* __restrict__ b_in,
  char* __restrict__ wsb)
{
  const int b = blockIdx.y;
  const int n = blockIdx.x*256 + threadIdx.x;
  if (n >= NN) return;
  const long row = (long)b*NN + n;
  float xr[36];
  {
    const float4* xp = (const float4*)(x + row*36);
    #pragma unroll
    for (int i=0;i<9;i++){ float4 t=xp[i]; xr[4*i]=t.x; xr[4*i+1]=t.y; xr[4*i+2]=t.z; xr[4*i+3]=t.w; }
  }
  int tidx = (int)(xr[34]*288.0f); tidx = tidx<0?0:(tidx>287?287:tidx);
  int widx = (int)(xr[35]);        widx = widx<0?0:(widx>6?6:widx);
  uint4* h0q = (uint4*)(wsb + H0B) + row*16;
  float hh[32];
  #pragma unroll 1
  for (int jj=0;jj<8;jj++){
    #pragma unroll
    for (int jl=0;jl<4;jl++){
      const int j = jj*4+jl;
      const float* w = W_in + j*36;
      float a0=0.f,a1=0.f,a2=0.f,a3=0.f;
      #pragma unroll
      for (int i=0;i<36;i+=4){ a0+=xr[i]*w[i]; a1+=xr[i+1]*w[i+1]; a2+=xr[i+2]*w[i+2]; a3+=xr[i+3]*w[i+3]; }
      hh[j] = b_in[j] + ((a0+a1)+(a2+a3));
    }
  }
  #pragma unroll
  for (int c=0;c<4;c++) h0q[c] = pk8(hh + 8*c);
  float xg[96];
  {
    const float4* p0 = (const float4*)(node_emb + (long)n*32);
    const float4* p1 = (const float4*)(time_emb + (long)tidx*32);
    const float4* p2 = (const float4*)(week_emb + (long)widx*32);
    #pragma unroll
    for (int i=0;i<8;i++){ float4 t=p0[i]; xg[4*i]=t.x; xg[4*i+1]=t.y; xg[4*i+2]=t.z; xg[4*i+3]=t.w; }
    #pragma unroll
    for (int i=0;i<8;i++){ float4 t=p1[i]; xg[32+4*i]=t.x; xg[32+4*i+1]=t.y; xg[32+4*i+2]=t.z; xg[32+4*i+3]=t.w; }
    #pragma unroll
    for (int i=0;i<8;i++){ float4 t=p2[i]; xg[64+4*i]=t.x; xg[64+4*i+1]=t.y; xg[64+4*i+2]=t.z; xg[64+4*i+3]=t.w; }
  }
  #pragma unroll
  for (int c=0;c<12;c++) h0q[4+c] = pk8(xg + 8*c);
}

// ---------- pass1b (MFMA): q, k', rm, global key max -----------------------
__global__ __launch_bounds__(256) void k_pass1b(
  const float* __restrict__ b1, const float* __restrict__ b2,
  char* __restrict__ wsb)
{
  __shared__ unsigned short xgt[64][104];
  __shared__ unsigned short dt[2][64][40];
  __shared__ unsigned short ot[64][72];
  __shared__ float wred[4];
  const int b   = blockIdx.y;
  const int tid = threadIdx.x;
  const int lane= tid & 63;
  const int w   = tid >> 6;
  const int c   = lane & 15;
  const int kg  = lane >> 4;
  const long r0blk = (long)blockIdx.x * 64;
  {
    int row = tid >> 2, q3 = tid & 3;
    long gr = r0blk + row;
    uint4 v0={0,0,0,0}, v1=v0, v2=v0;
    if (gr < NN){
      const uint4* src = (const uint4*)(wsb + H0B + ((long)b*NN + gr)*256 + 64 + q3*48);
      v0=src[0]; v1=src[1]; v2=src[2];
    }
    uint4* d = (uint4*)&xgt[row][q3*24];
    d[0]=v0; d[1]=v1; d[2]=v2;
  }
  __syncthreads();
  const unsigned short* w1bf = (const unsigned short*)(wsb + W12B);
  const unsigned short* w2bf = w1bf + 3072;
  const unsigned short* pjbf = w1bf + 6144;
  f32x4 accd[2][2];
  #pragma unroll
  for (int s=0;s<2;s++)
    #pragma unroll
    for (int f=0;f<2;f++) accd[s][f] = (f32x4){0.f,0.f,0.f,0.f};
  #pragma unroll
  for (int ks=0;ks<3;ks++){
    short8_t a = *(const short8_t*)&xgt[w*16 + c][ks*32 + kg*8];
    #pragma unroll
    for (int f=0;f<2;f++){
      short8_t bw1 = *(const short8_t*)(w1bf + (f*16+c)*96 + ks*32 + kg*8);
      accd[0][f] = __builtin_amdgcn_mfma_f32_16x16x32_bf16(a, bw1, accd[0][f], 0,0,0);
      short8_t bw2 = *(const short8_t*)(w2bf + (f*16+c)*96 + ks*32 + kg*8);
      accd[1][f] = __builtin_amdgcn_mfma_f32_16x16x32_bf16(a, bw2, accd[1][f], 0,0,0);
    }
  }
  const float DSC = 0.42044820762685725f;   // 32^-0.25
  float dv[2][2][4];
  #pragma unroll
  for (int f=0;f<2;f++){
    float bb1 = b1[f*16+c], bb2 = b2[f*16+c];
    #pragma unroll
    for (int jj=0;jj<4;jj++){
      dv[0][f][jj] = (accd[0][f][jj] + bb1) * DSC;
      dv[1][f][jj] = (accd[1][f][jj] + bb2) * DSC;
    }
  }
  float dg[2][4];
  #pragma unroll
  for (int s=0;s<2;s++)
    #pragma unroll
    for (int jj=0;jj<4;jj++){
      float t = dv[s][0][jj]*dv[s][0][jj] + dv[s][1][jj]*dv[s][1][jj];
      #pragma unroll
      for (int off=1; off<16; off<<=1) t += __shfl_xor(t, off);
      dg[s][jj] = 0.5f * t;
    }
  #pragma unroll
  for (int s=0;s<2;s++)
    #pragma unroll
    for (int f=0;f<2;f++)
      #pragma unroll
      for (int jj=0;jj<4;jj++)
        dt[s][w*16 + kg*4 + jj][f*16 + c] = f2bf(dv[s][f][jj]);
  __syncthreads();
  f32x4 acc2[2][4];
  #pragma unroll
  for (int s=0;s<2;s++){
    short8_t ad = *(const short8_t*)&dt[s][w*16 + c][kg*8];
    #pragma unroll
    for (int f=0;f<4;f++){
      short8_t bp = *(const short8_t*)(pjbf + (f*16+c)*32 + kg*8);
      acc2[s][f] = __builtin_amdgcn_mfma_f32_16x16x32_bf16(ad, bp, (f32x4){0.f,0.f,0.f,0.f}, 0,0,0);
    }
  }
  float mx[2][4];
  #pragma unroll
  for (int s=0;s<2;s++)
    #pragma unroll
    for (int jj=0;jj<4;jj++){
      float t = fmaxf(fmaxf(acc2[s][0][jj],acc2[s][1][jj]),
                      fmaxf(acc2[s][2][jj],acc2[s][3][jj]));
      #pragma unroll
      for (int off=1; off<16; off<<=1) t = fmaxf(t, __shfl_xor(t, off));
      mx[s][jj] = t;
    }
  #pragma unroll
  for (int f=0;f<4;f++)
    #pragma unroll
    for (int jj=0;jj<4;jj++){
      float qv = 0.125f*(__expf(acc2[0][f][jj] - dg[0][jj] - mx[0][jj]) + 1e-6f);
      ot[w*16 + kg*4 + jj][f*16 + c] = f2bf(qv);
    }
  __syncthreads();
  {
    int row = tid >> 2, q3 = tid & 3;
    long gr = r0blk + row;
    if (gr < NN){
      const uint4* s = (const uint4*)&ot[row][q3*16];
      uint4* dst = (uint4*)((unsigned short*)(wsb + QB) + ((long)b*NN + gr)*64 + q3*16);
      dst[0] = s[0]; dst[1] = s[1];
    }
  }
  __syncthreads();
  float bmax = -3.0e38f;
  #pragma unroll
  for (int f=0;f<4;f++)
    #pragma unroll
    for (int jj=0;jj<4;jj++){
      float kv = __expf(acc2[1][f][jj] - mx[1][jj]);
      ot[w*16 + kg*4 + jj][f*16 + c] = f2bf(kv);
    }
  #pragma unroll
  for (int jj=0;jj<4;jj++){
    long gr = r0blk + w*16 + kg*4 + jj;
    bool val = (gr < NN);
    if (val && c==0)
      ((float*)(wsb + RMB))[(long)b*NN + gr] = mx[1][jj] - dg[1][jj];
    if (val) bmax = fmaxf(bmax, mx[1][jj]);
  }
  #pragma unroll
  for (int off=32; off>0; off>>=1) bmax = fmaxf(bmax, __shfl_xor(bmax, off));
  if (lane==0) wred[w] = bmax;
  __syncthreads();
  {
    int row = tid >> 2, q3 = tid & 3;
    long gr = r0blk + row;
    if (gr < NN){
      const uint4* s = (const uint4*)&ot[row][q3*16];
      uint4* dst = (uint4*)((unsigned short*)(wsb + KKB) + ((long)b*NN + gr)*64 + q3*16);
      dst[0] = s[0]; dst[1] = s[1];
    }
  }
  if (tid==0){
    float m2 = fmaxf(fmaxf(wred[0],wred[1]), fmaxf(wred[2],wred[3]));
    atomicMax((unsigned*)(wsb + GMB) + b, encOrd(m2));
  }
}

// ---------- fused GLU + k-finalize (+ksum) + MFMA reduce -------------------
// round-13 shape + ktl XOR-swizzle (16B blocks) + next-tile prefetch
__global__ __launch_bounds__(256) void k_glured(
  char* __restrict__ wsb, const unsigned short* __restrict__ hsrc,
  const unsigned short* __restrict__ wbf,
  const float* __restrict__ bi, const float* __restrict__ bo,
  float* __restrict__ v2x_out, float* __restrict__ ksout)
{
  __shared__ unsigned short pool[9216];        // ht[64][136] alias htT[128][72]
  __shared__ unsigned short ktl[64][72];       // finalized k^T, XOR-swizzled 16B blocks
  __shared__ float red[256];
  unsigned short (*ht)[136] = (unsigned short(*)[136])pool;
  unsigned short (*htT)[72] = (unsigned short(*)[72])pool;
  const int b = blockIdx.y;
  const int tid = threadIdx.x;
  const int lane = tid & 63;
  const int w = tid >> 6;
  const int c = lane & 15;
  const int kg = lane >> 4;
  const float gm = decOrd(((const unsigned*)(wsb + GMB))[b]);
  const float* rm = (const float*)(wsb + RMB) + (long)b*NN;
  const uint4* kbase = (const uint4*)(wsb + KKB) + (long)b*NN*8;
  f32x4 racc[8];
  #pragma unroll
  for (int f=0;f<8;f++) racc[f] = (f32x4){0.f,0.f,0.f,0.f};
  float ksacc = 0.f;
  float bi_l[8], bo_l[8];
  #pragma unroll
  for (int f=0;f<8;f++){ bi_l[f] = bi[f*16+c]; bo_l[f] = bo[f*16+c]; }
  const int krr = tid>>3, kcc = tid&7;
  const int srow = tid>>2, sq3 = tid&3;
  const int rswz = ((w*16 + c) >> 3) & 7;      // reduce-read swizzle for this thread's row
  // ---- preload tile 0 ----
  uint4 hv0,hv1,hv2,hv3, krA,krB; float rmA,rmB;
  {
    const long r0 = (long)blockIdx.x*256;
    long gr = r0 + srow;
    hv0=(uint4){0,0,0,0}; hv1=hv0; hv2=hv0; hv3=hv0;
    if (gr < NN){
      const uint4* s = (const uint4*)(hsrc + ((long)b*NN + gr)*128 + sq3*32);
      hv0=s[0]; hv1=s[1]; hv2=s[2]; hv3=s[3];
    }
    krA=(uint4){0,0,0,0}; krB=krA; rmA=0.f; rmB=0.f;
    long gA = r0 + krr;      if (gA < NN){ krA = kbase[gA*8 + kcc]; rmA = rm[gA]; }
    long gB = r0 + krr + 32; if (gB < NN){ krB = kbase[gB*8 + kcc]; rmB = rm[gB]; }
  }
  #pragma unroll 1
  for (int t=0;t<4;t++){
    const long r0 = (long)blockIdx.x*256 + t*64;
    { // write h tile from prefetched regs
      uint4* d = (uint4*)&ht[srow][sq3*32];
      d[0]=hv0; d[1]=hv1; d[2]=hv2; d[3]=hv3;
    }
    { // finalize + write k^T (swizzled) from prefetched regs
      bool vA = (r0 + krr) < NN;
      bool vB = (r0 + krr + 32) < NN;
      float sA = __expf(rmA - gm), sB = __expf(rmB - gm);
      float ta[8], tb[8];
      up8(krA, ta); up8(krB, tb);
      #pragma unroll
      for (int i=0;i<8;i++){
        ta[i] = vA ? 0.125f*(ta[i]*sA + 1e-6f) : 0.f;
        tb[i] = vB ? 0.125f*(tb[i]*sB + 1e-6f) : 0.f;
      }
      const int pA = (((krr>>3) ^ kcc) << 3) | (krr & 7);
      const int pB = ((((krr>>3)+4) ^ kcc) << 3) | (krr & 7);
      #pragma unroll
      for (int i=0;i<8;i++){
        ktl[kcc*8+i][pA] = f2bf(ta[i]);
        ktl[kcc*8+i][pB] = f2bf(tb[i]);
      }
    }
    // prefetch tile t+1 (lands during GLU+reduce)
    if (t < 3){
      const long r1 = r0 + 64;
      long gr = r1 + srow;
      hv0=(uint4){0,0,0,0}; hv1=hv0; hv2=hv0; hv3=hv0;
      if (gr < NN){
        const uint4* s = (const uint4*)(hsrc + ((long)b*NN + gr)*128 + sq3*32);
        hv0=s[0]; hv1=s[1]; hv2=s[2]; hv3=s[3];
      }
      krA=(uint4){0,0,0,0}; krB=krA; rmA=0.f; rmB=0.f;
      long gA = r1 + krr;      if (gA < NN){ krA = kbase[gA*8 + kcc]; rmA = rm[gA]; }
      long gB = r1 + krr + 32; if (gB < NN){ krB = kbase[gB*8 + kcc]; rmB = rm[gB]; }
    }
    __syncthreads();
    // GLU MFMA (full gacc[16] — empirically fastest allocation)
    f32x4 gacc[16];
    #pragma unroll
    for (int f=0;f<16;f++) gacc[f] = (f32x4){0.f,0.f,0.f,0.f};
    #pragma unroll
    for (int ks=0;ks<4;ks++){
      short8_t a = *(const short8_t*)&ht[w*16 + c][ks*32 + kg*8];
      #pragma unroll
      for (int f=0;f<16;f++){
        short8_t bb = *(const short8_t*)(wbf + (f*16 + c)*128 + ks*32 + kg*8);
        gacc[f] = __builtin_amdgcn_mfma_f32_16x16x32_bf16(a, bb, gacc[f], 0, 0, 0);
      }
    }
    float ov[8][4];
    #pragma unroll
    for (int f=0;f<8;f++)
      #pragma unroll
      for (int j=0;j<4;j++){
        float aa = gacc[f][j]   + bi_l[f];
        float cc2= gacc[f+8][j] + bo_l[f];
        ov[f][j] = cc2 / (1.0f + __expf(-aa));
      }
    if (ksout){ // ksum partial from ktl (swizzle-aware)
      int m = tid & 63, n0 = (tid>>6)*16;
      int sm = (m>>3)&7;
      #pragma unroll
      for (int n=0;n<16;n++){
        int nn = n0+n;
        ksacc += bf2f(ktl[m][(((nn>>3)^sm)<<3)|(nn&7)]);
      }
    }
    __syncthreads();   // ht reads done (htT aliases)
    // write v transposed (zero OOB rows)
    #pragma unroll
    for (int f=0;f<8;f++)
      #pragma unroll
      for (int j=0;j<4;j++){
        bool val = (r0 + w*16 + kg*4 + j) < NN;
        htT[f*16 + c][w*16 + kg*4 + j] = val ? f2bf(ov[f][j]) : (unsigned short)0;
      }
    __syncthreads();
    // reduce MFMA: wave w -> out rows m = w*16..+15 (A from swizzled ktl)
    #pragma unroll
    for (int ks=0;ks<2;ks++){
      short8_t a0 = *(const short8_t*)&ktl[w*16 + c][((ks*4 + 0) ^ rswz) << 3];
      // NOTE: per-kg block: each lane reads its own kg block
      short8_t a = *(const short8_t*)&ktl[w*16 + c][((ks*4 + kg) ^ rswz) << 3];
      (void)a0;
      #pragma unroll
      for (int f=0;f<8;f++){
        short8_t bb = *(const short8_t*)&htT[f*16 + c][ks*32 + kg*8];
        racc[f] = __builtin_amdgcn_mfma_f32_16x16x32_bf16(a, bb, racc[f], 0, 0, 0);
      }
    }
    __syncthreads();   // loop-end WAR
  }
  float* v2x = v2x_out + (long)b*8192;
  #pragma unroll
  for (int f=0;f<8;f++)
    #pragma unroll
    for (int j=0;j<4;j++)
      atomicAdd(&v2x[(w*16 + kg*4 + j)*128 + f*16 + c], racc[f][j]);
  if (ksout){
    red[tid] = ksacc;
    __syncthreads();
    if (tid < 64)
      atomicAdd(ksout + b*64 + tid,
                red[tid]+red[64+tid]+red[128+tid]+red[192+tid]);
  }
}

// ---------- v2t[b][n][m]: n<128: v2x[m][n]; n=128: ksum[m]; n>128: 0 -------
__global__ void k_v2cvt(char* __restrict__ wsb, const float* __restrict__ v2f){
  int idx = blockIdx.x*256 + threadIdx.x;          // 36864
  if (idx >= 36864) return;
  int b = idx / 9216, rem = idx % 9216;
  int n = rem / 64, m = rem % 64;
  const float* ks = (const float*)(wsb + KSB);
  float v = (n < 128) ? v2f[b*8192 + m*128 + n] : ((n==128) ? ks[b*64+m] : 0.f);
  ((unsigned short*)(wsb + V2TB))[b*9216 + n*64 + m] = f2bf(v);
}

// ---------- attn0 + residual(h0) + LN0 -> h1 -------------------------------
__global__ __launch_bounds__(256, 4) void k_attnln(
  char* __restrict__ wsb, const float* __restrict__ g0,
  const float* __restrict__ bt0)
{
  __shared__ unsigned short ht[64][132];    // 16896 B
  __shared__ unsigned short v2s[144*72];    // 20736 B
  const int b = blockIdx.y;
  const int tid = threadIdx.x;
  const int lane = tid & 63;
  const int w  = tid >> 6;
  const int c  = lane & 15;
  const int kg = lane >> 4;
  const long r0blk = (long)blockIdx.x*64;
  const long r0w = r0blk + w*16;
  const int rrow = tid>>2, rq3 = tid&3;
  const long rgr = r0blk + rrow;
  short8_t aq0, aq1;
  if (r0w + c < NN){
    const unsigned short* qrow = (const unsigned short*)(wsb + QB) + ((long)b*NN + r0w + c)*64 + kg*8;
    aq0 = *(const short8_t*)qrow; aq1 = *(const short8_t*)(qrow + 32);
  } else {
    aq0 = (short8_t){0,0,0,0,0,0,0,0}; aq1 = aq0;
  }
  uint4 rh0={0,0,0,0}, rh1={0,0,0,0}, rh2={0,0,0,0}, rh3={0,0,0,0};
  if (rgr < NN){
    const uint4* hs = (const uint4*)((const unsigned short*)(wsb + H0B) + ((long)b*NN + rgr)*128 + rq3*32);
    rh0=hs[0]; rh1=hs[1]; rh2=hs[2]; rh3=hs[3];
  }
  {
    const uint4* v2g = (const uint4*)((const unsigned short*)(wsb + V2TB) + b*9216);
    #pragma unroll
    for (int e=0;e<5;e++){
      int j = tid + 256*e;
      if (j < 1152){
        int row = j >> 3, cc = j & 7;
        *(uint4*)&v2s[row*72 + cc*8] = v2g[j];
      }
    }
  }
  __syncthreads();
  f32x4 acc[9];
  #pragma unroll
  for (int f=0;f<9;f++) acc[f] = (f32x4){0.f,0.f,0.f,0.f};
  #pragma unroll
  for (int f=0;f<9;f++){
    short8_t b0 = *(const short8_t*)&v2s[(f*16 + c)*72 + kg*8];
    acc[f] = __builtin_amdgcn_mfma_f32_16x16x32_bf16(aq0, b0, acc[f], 0, 0, 0);
    short8_t b1v = *(const short8_t*)&v2s[(f*16 + c)*72 + 32 + kg*8];
    acc[f] = __builtin_amdgcn_mfma_f32_16x16x32_bf16(aq1, b1v, acc[f], 0, 0, 0);
  }
  float inv[4];
  #pragma unroll
  for (int j=0;j<4;j++) inv[j] = 1.0f / __shfl(acc[8][j], (lane & 48));
  #pragma unroll
  for (int f=0;f<8;f++)
    #pragma unroll
    for (int j=0;j<4;j++)
      ht[w*16 + kg*4 + j][f*16 + c] = f2bf(acc[f][j]*inv[j]);
  __syncthreads();
  // row-owner: residual(regs) + LN0 -> h1 (global)
  {
    float tv[32];
    {
      const uint4* os = (const uint4*)&ht[rrow][rq3*32];
      uint4 o0=os[0],o1=os[1],o2=os[2],o3=os[3];
      up8(o0,tv); up8(o1,tv+8); up8(o2,tv+16); up8(o3,tv+24);
    }
    {
      float hv[32];
      up8(rh0,hv); up8(rh1,hv+8); up8(rh2,hv+16); up8(rh3,hv+24);
      #pragma unroll
      for (int i=0;i<32;i++) tv[i] += hv[i];
    }
    float s = 0.f;
    #pragma unroll
    for (int i=0;i<32;i++) s += tv[i];
    s += __shfl_xor(s, 1); s += __shfl_xor(s, 2);
    float mu = s * (1.0f/128.0f);
    float vv = 0.f;
    #pragma unroll
    for (int i=0;i<32;i++){ float e = tv[i]-mu; vv += e*e; }
    vv += __shfl_xor(vv, 1); vv += __shfl_xor(vv, 2);
    float rs = rsqrtf(vv * (1.0f/128.0f) + 1e-5f);
    const float4* gp = (const float4*)(g0 + rq3*32);
    const float4* bp = (const float4*)(bt0 + rq3*32);
    float h1v[32];
    #pragma unroll
    for (int i8=0;i8<8;i8++){
      float4 g4 = gp[i8], b4 = bp[i8];
      h1v[i8*4  ] = (tv[i8*4  ]-mu)*rs*g4.x + b4.x;
      h1v[i8*4+1] = (tv[i8*4+1]-mu)*rs*g4.y + b4.y;
      h1v[i8*4+2] = (tv[i8*4+2]-mu)*rs*g4.z + b4.z;
      h1v[i8*4+3] = (tv[i8*4+3]-mu)*rs*g4.w + b4.w;
    }
    if (rgr < NN){
      uint4 p0=pk8(h1v), p1=pk8(h1v+8), p2=pk8(h1v+16), p3=pk8(h1v+24);
      uint4* dst = (uint4*)((unsigned short*)(wsb + H1B) + ((long)b*NN + rgr)*128 + rq3*32);
      dst[0]=p0; dst[1]=p1; dst[2]=p2; dst[3]=p3;
    }
  }
}

// ---------- attn1 + residual(h1) + LN1 + MFMA regression head --------------
__global__ __launch_bounds__(256) void k_attnhead(
  char* __restrict__ wsb, const float* __restrict__ g1,
  const float* __restrict__ bt1, const float* __restrict__ b_reg,
  float* __restrict__ out)
{
  __shared__ unsigned short ht[64][132];
  __shared__ unsigned short v2s[144*72];    // reused as h0 tile [64][136]
  const int b = blockIdx.y;
  const int tid = threadIdx.x;
  const int lane = tid & 63;
  const int w  = tid >> 6;
  const int c  = lane & 15;
  const int kg = lane >> 4;
  const long r0blk = (long)blockIdx.x*64;
  const long r0w = r0blk + w*16;
  const int rrow = tid>>2, rq3 = tid&3;
  const long rgr = r0blk + rrow;
  short8_t aq0, aq1;
  if (r0w + c < NN){
    const unsigned short* qrow = (const unsigned short*)(wsb + QB) + ((long)b*NN + r0w + c)*64 + kg*8;
    aq0 = *(const short8_t*)qrow; aq1 = *(const short8_t*)(qrow + 32);
  } else {
    aq0 = (short8_t){0,0,0,0,0,0,0,0}; aq1 = aq0;
  }
  uint4 rh0={0,0,0,0}, rh1={0,0,0,0}, rh2={0,0,0,0}, rh3={0,0,0,0};
  uint4 ah0={0,0,0,0}, ah1={0,0,0,0}, ah2={0,0,0,0}, ah3={0,0,0,0};
  if (rgr < NN){
    const uint4* hs = (const uint4*)((const unsigned short*)(wsb + H1B) + ((long)b*NN + rgr)*128 + rq3*32);
    rh0=hs[0]; rh1=hs[1]; rh2=hs[2]; rh3=hs[3];
    const uint4* h0s = (const uint4*)((const unsigned short*)(wsb + H0B) + ((long)b*NN + rgr)*128 + rq3*32);
    ah0=h0s[0]; ah1=h0s[1]; ah2=h0s[2]; ah3=h0s[3];
  }
  {
    const uint4* v2g = (const uint4*)((const unsigned short*)(wsb + V2TB) + b*9216);
    #pragma unroll
    for (int e=0;e<5;e++){
      int j = tid + 256*e;
      if (j < 1152){
        int row = j >> 3, cc = j & 7;
        *(uint4*)&v2s[row*72 + cc*8] = v2g[j];
      }
    }
  }
  __syncthreads();
  f32x4 acc[9];
  #pragma unroll
  for (int f=0;f<9;f++) acc[f] = (f32x4){0.f,0.f,0.f,0.f};
  #pragma unroll
  for (int f=0;f<9;f++){
    short8_t b0 = *(const short8_t*)&v2s[(f*16 + c)*72 + kg*8];
    acc[f] = __builtin_amdgcn_mfma_f32_16x16x32_bf16(aq0, b0, acc[f], 0, 0, 0);
    short8_t b1v = *(const short8_t*)&v2s[(f*16 + c)*72 + 32 + kg*8];
    acc[f] = __builtin_amdgcn_mfma_f32_16x16x32_bf16(aq1, b1v, acc[f], 0, 0, 0);
  }
  float inv[4];
  #pragma unroll
  for (int j=0;j<4;j++) inv[j] = 1.0f / __shfl(acc[8][j], (lane & 48));
  #pragma unroll
  for (int f=0;f<8;f++)
    #pragma unroll
    for (int j=0;j<4;j++)
      ht[w*16 + kg*4 + j][f*16 + c] = f2bf(acc[f][j]*inv[j]);
  __syncthreads();   // v2s reads done -> reuse as h0 tile
  {
    unsigned short* h0t = v2s;
    uint4* hd = (uint4*)&h0t[rrow*136 + rq3*32];
    hd[0]=ah0; hd[1]=ah1; hd[2]=ah2; hd[3]=ah3;
    float tv[32];
    {
      const uint4* os = (const uint4*)&ht[rrow][rq3*32];
      uint4 o0=os[0],o1=os[1],o2=os[2],o3=os[3];
      up8(o0,tv); up8(o1,tv+8); up8(o2,tv+16); up8(o3,tv+24);
    }
    {
      float hv[32];
      up8(rh0,hv); up8(rh1,hv+8); up8(rh2,hv+16); up8(rh3,hv+24);
      #pragma unroll
      for (int i=0;i<32;i++) tv[i] += hv[i];
    }
    float s = 0.f;
    #pragma unroll
    for (int i=0;i<32;i++) s += tv[i];
    s += __shfl_xor(s, 1); s += __shfl_xor(s, 2);
    float mu = s * (1.0f/128.0f);
    float vv = 0.f;
    #pragma unroll
    for (int i=0;i<32;i++){ float e = tv[i]-mu; vv += e*e; }
    vv += __shfl_xor(vv, 1); vv += __shfl_xor(vv, 2);
    float rs = rsqrtf(vv * (1.0f/128.0f) + 1e-5f);
    const float4* gp = (const float4*)(g1 + rq3*32);
    const float4* bp = (const float4*)(bt1 + rq3*32);
    float h2v[32];
    #pragma unroll
    for (int i8=0;i8<8;i8++){
      float4 g4 = gp[i8], b4 = bp[i8];
      h2v[i8*4  ] = fmaxf((tv[i8*4  ]-mu)*rs*g4.x + b4.x, 0.f);
      h2v[i8*4+1] = fmaxf((tv[i8*4+1]-mu)*rs*g4.y + b4.y, 0.f);
      h2v[i8*4+2] = fmaxf((tv[i8*4+2]-mu)*rs*g4.z + b4.z, 0.f);
      h2v[i8*4+3] = fmaxf((tv[i8*4+3]-mu)*rs*g4.w + b4.w, 0.f);
    }
    uint4 p0=pk8(h2v), p1=pk8(h2v+8), p2=pk8(h2v+16), p3=pk8(h2v+24);
    uint4* d = (uint4*)&ht[rrow][rq3*32];
    d[0]=p0; d[1]=p1; d[2]=p2; d[3]=p3;
  }
  __syncthreads();
  const unsigned short* wregT = (const unsigned short*)(wsb + W12B) + 8192;
  const unsigned short* h0t = v2s;
  f32x4 hacc = (f32x4){0.f,0.f,0.f,0.f};
  #pragma unroll
  for (int ks=0;ks<8;ks++){
    short8_t a;
    if (ks < 4)
      a = relu8(*(const short8_t*)&h0t[(w*16 + c)*136 + ks*32 + kg*8]);
    else
      a = *(const short8_t*)&ht[w*16 + c][(ks-4)*32 + kg*8];
    short8_t bb = *(const short8_t*)(wregT + c*256 + ks*32 + kg*8);
    hacc = __builtin_amdgcn_mfma_f32_16x16x32_bf16(a, bb, hacc, 0, 0, 0);
  }
  if (c < 12){
    float br = b_reg[c];
    #pragma unroll
    for (int j=0;j<4;j++){
      long gr = r0w + kg*4 + j;
      if (gr < NN)
        out[((long)b*12 + c)*NN + gr] = hacc[j] + br;
    }
  }
}

extern "C" void kernel_launch(void* const* d_in, const int* in_sizes, int n_in,
                              void* d_out, int out_size, void* d_ws, size_t ws_size,
                              hipStream_t stream)
{
  const float* x        = (const float*)d_in[0];
  const float* node_emb = (const float*)d_in[1];
  const float* time_emb = (const float*)d_in[2];
  const float* week_emb = (const float*)d_in[3];
  const float* W_in     = (const float*)d_in[4];
  const float* b_in     = (const float*)d_in[5];
  const float* W1       = (const float*)d_in[6];
  const float* b1       = (const float*)d_in[7];
  const float* W2       = (const float*)d_in[8];
  const float* b2       = (const float*)d_in[9];
  const float* W_reg    = (const float*)d_in[10];
  const float* b_reg    = (const float*)d_in[11];
  const float* proj     = (const float*)d_in[12];
  const float* fc_in0_w = (const float*)d_in[13];
  const float* fc_in0_b = (const float*)d_in[14];
  const float* fc_out0_w= (const float*)d_in[15];
  const float* fc_out0_b= (const float*)d_in[16];
  const float* ln0_g    = (const float*)d_in[17];
  const float* ln0_b    = (const float*)d_in[18];
  const float* fc_in1_w = (const float*)d_in[19];
  const float* fc_in1_b = (const float*)d_in[20];
  const float* fc_out1_w= (const float*)d_in[21];
  const float* fc_out1_b= (const float*)d_in[22];
  const float* ln1_g    = (const float*)d_in[23];
  const float* ln1_b    = (const float*)d_in[24];
  char* wsb  = (char*)d_ws;
  float* out = (float*)d_out;

  dim3 rowgrid((NN+255)/256, NB);     // (196, 4)
  dim3 atngrid(782, NB);              // 782*64 = 50048 >= NN
  dim3 fgrid0(196, NB);               // 196*256 = 50176, 4 tiles/block
  dim3 cvtgrid(144);

  k_init  <<<258, 256, 0, stream>>>(wsb);
  k_wcvt  <<<256, 256, 0, stream>>>(fc_in0_w, fc_out0_w, fc_in1_w, fc_out1_w, wsb);
  k_wcvt2 <<<48, 256, 0, stream>>>(W1, W2, proj, W_reg, wsb);
  k_pass1a<<<rowgrid, 256, 0, stream>>>(x, node_emb, time_emb, week_emb,
                                        W_in, b_in, wsb);
  k_pass1b<<<atngrid, 256, 0, stream>>>(b1, b2, wsb);
  k_glured<<<fgrid0, 256, 0, stream>>>(wsb, (const unsigned short*)(wsb + H0B),
                                       (const unsigned short*)(wsb + WBFB),
                                       fc_in0_b, fc_out0_b,
                                       (float*)(wsb + V2F0B), (float*)(wsb + KSB));
  k_v2cvt <<<cvtgrid, 256, 0, stream>>>(wsb, (const float*)(wsb + V2F0B));
  k_attnln<<<atngrid, 256, 0, stream>>>(wsb, ln0_g, ln0_b);
  k_glured<<<fgrid0, 256, 0, stream>>>(wsb, (const unsigned short*)(wsb + H1B),
                                       (const unsigned short*)(wsb + WBFB) + 32768,
                                       fc_in1_b, fc_out1_b,
                                       (float*)(wsb + V2F1B), (float*)nullptr);
  k_v2cvt <<<cvtgrid, 256, 0, stream>>>(wsb, (const float*)(wsb + V2F1B));
  k_attnhead<<<atngrid, 256, 0, stream>>>(wsb, ln1_g, ln1_b, b_reg, out);
}